// Round 6
// baseline (202.984 us; speedup 1.0000x reference)
//
#include <hip/hip_runtime.h>
#include <math.h>

typedef __attribute__((ext_vector_type(8))) short bf16x8;
typedef __attribute__((ext_vector_type(4))) float f32x4;

#define RFEAT 256
#define ZN 20480                        // 256 feats x 80 cols (64 v + ksum + 15 pad)
#define NBKV 1024                       // kv blocks; 1 chunk of 64 rows each -> 4 blocks/CU

// exp2-domain: phi = ratio * exp(x.P'*sc - sc^2*||x||^2/2) = 2^( mfma(x, sc*log2e*P) + rc )
// rc = -0.5*sc^2*log2e*||x||^2 + log2(ratio);  sc = 64^-0.25 = 2^-1.5, ratio = 1/16
#define SCLOG2E 0.51006971688f          // sc * log2(e)
#define RC_COEF -0.09016844006f         // -0.5 * sc^2 * log2(e)
#define LOG2RATIO -4.0f                 // log2(1/16)

__device__ __forceinline__ unsigned short f2bf(float f) {
    union { float f; unsigned int u; } v; v.f = f;
    unsigned int r = v.u + 0x7FFFu + ((v.u >> 16) & 1u);   // RNE
    return (unsigned short)(r >> 16);
}

// ---------------- prep: Vb frags + Pb frags + zero Zf ----------------
// Vb frag F = s*4+nt, lane l, elem j: B[k][n] = V[s*32 + (l>>4)*8 + j][nt*16 + (l&15)].
// Pb frag f = kstep*16+nt: B[k][n] = SCLOG2E*P[n][k], n = nt*16+(l&15), k = kstep*32+(l>>4)*8+j.
__global__ __launch_bounds__(256)
void prep_kernel(const float* __restrict__ P, const float* __restrict__ V,
                 unsigned short* __restrict__ Pb, unsigned short* __restrict__ Vb,
                 float* __restrict__ Zf)
{
    const int t = threadIdx.x, l = t & 63;
    if (blockIdx.x < 2048) {            // Vb: 2048 blocks x 4 waves = 8192 frags
        const int F = blockIdx.x * 4 + (t >> 6);
        const float* src = V + (size_t)((F >> 2) * 32 + (l >> 4) * 8) * 64 + (F & 3) * 16 + (l & 15);
        bf16x8 fr;
        #pragma unroll
        for (int j = 0; j < 8; j++) fr[j] = (short)f2bf(src[j * 64]);
        *(bf16x8*)(Vb + (size_t)F * 512 + l * 8) = fr;
        return;
    }
    if (blockIdx.x == 2048) {           // Pb (one block, 4 waves x 8 frags)
        const int g = t >> 6;
        for (int f = g * 8; f < g * 8 + 8; f++) {
            const int kstep = f >> 4, nt = f & 15;
            const float* src = P + (nt * 16 + (l & 15)) * 64 + kstep * 32 + (l >> 4) * 8;
            bf16x8 frag;
            #pragma unroll
            for (int j = 0; j < 8; j++) frag[j] = (short)f2bf(SCLOG2E * src[j]);
            *(bf16x8*)(Pb + f * 512 + l * 8) = frag;
        }
        return;
    }
    // zero Zf: blocks 2049..2128
    const int idx = (blockIdx.x - 2049) * 256 + t;
    Zf[idx] = 0.f;
}

// ---------------- phi of a 64-row chunk -> LDS (bf16), via MFMA ----------------
// TRANS=true : phi_lds[col*LDP + row]  (packed u32 writes; for kv stage)
// TRANS=false: phi_lds[row*LDP + col]  (for q stage)
template<int LDP, bool TRANS>
__device__ __forceinline__ void phi_chunk(const float* __restrict__ X, int chunkBase,
                                          const unsigned short* __restrict__ Pb,
                                          unsigned short* phi_lds, float* rc)
{
    const int t = threadIdx.x, l = t & 63, w = t >> 6;
    if (t < 64) {   // per-row constant (exp2 domain)
        const float4* xr = (const float4*)(X + (size_t)(chunkBase + t) * 64);
        float s0 = 0.f, s1 = 0.f;
        #pragma unroll
        for (int j = 0; j < 16; j += 2) {
            float4 a = xr[j];     s0 += a.x*a.x + a.y*a.y + a.z*a.z + a.w*a.w;
            float4 b = xr[j + 1]; s1 += b.x*b.x + b.y*b.y + b.z*b.z + b.w*b.w;
        }
        rc[t] = RC_COEF * (s0 + s1) + LOG2RATIO;
    }
    // A-frags: wave w owns rows [chunkBase+16w, +16); m = l&15, k = (l>>4)*8 + j (+32 for kstep 1)
    const float* ar = X + (size_t)(chunkBase + 16 * w + (l & 15)) * 64 + (l >> 4) * 8;
    bf16x8 a0, a1;
    #pragma unroll
    for (int j = 0; j < 8; j++) a0[j] = (short)f2bf(ar[j]);
    #pragma unroll
    for (int j = 0; j < 8; j++) a1[j] = (short)f2bf(ar[32 + j]);
    __syncthreads();   // rc ready
    const float4 rcv = *(const float4*)(rc + 16 * w + 4 * (l >> 4));   // rc rows for D regs 0..3
    #pragma unroll
    for (int nt = 0; nt < 16; nt++) {
        bf16x8 b0 = *(const bf16x8*)(Pb + nt * 512 + l * 8);
        bf16x8 b1 = *(const bf16x8*)(Pb + (16 + nt) * 512 + l * 8);
        f32x4 acc = (f32x4){rcv.x, rcv.y, rcv.z, rcv.w};   // C-in = rc (free add)
        acc = __builtin_amdgcn_mfma_f32_16x16x32_bf16(a0, b0, acc, 0, 0, 0);
        acc = __builtin_amdgcn_mfma_f32_16x16x32_bf16(a1, b1, acc, 0, 0, 0);
        float p0 = __builtin_amdgcn_exp2f(acc[0]);
        float p1 = __builtin_amdgcn_exp2f(acc[1]);
        float p2 = __builtin_amdgcn_exp2f(acc[2]);
        float p3 = __builtin_amdgcn_exp2f(acc[3]);
        const int col = nt * 16 + (l & 15);
        unsigned int w0 = (unsigned int)f2bf(p0) | ((unsigned int)f2bf(p1) << 16);
        unsigned int w1 = (unsigned int)f2bf(p2) | ((unsigned int)f2bf(p3) << 16);
        if (TRANS) {   // rows (l>>4)*4 + 0..3 contiguous -> 2 packed u32 writes
            unsigned int* dst = (unsigned int*)(phi_lds + col * LDP + 16 * w + 4 * (l >> 4));
            dst[0] = w0;
            dst[1] = w1;
        } else {
            const int rb = (16 * w + (l >> 4) * 4) * LDP + col;
            phi_lds[rb]           = (unsigned short)(w0);
            phi_lds[rb + LDP]     = (unsigned short)(w0 >> 16);
            phi_lds[rb + 2 * LDP] = (unsigned short)(w1);
            phi_lds[rb + 3 * LDP] = (unsigned short)(w1 >> 16);
        }
    }
    __syncthreads();
}

// ---------------- kv_atomic: Zf += phi(K)^T @ [V | 1] over this block's 64 rows ----------------
__global__ __launch_bounds__(256, 4)
void kv_atomic_kernel(const float* __restrict__ Kp, const unsigned short* __restrict__ Vb,
                      const unsigned short* __restrict__ Pb, float* __restrict__ Zf)
{
    __shared__ __align__(16) unsigned short phi_lds[RFEAT * 72];   // [feat][krow], padded
    __shared__ __align__(16) float rc[64];
    const int t = threadIdx.x, l = t & 63, w = t >> 6;

    f32x4 acc[4][5];
    #pragma unroll
    for (int mt = 0; mt < 4; mt++)
        #pragma unroll
        for (int nt = 0; nt < 5; nt++) acc[mt][nt] = (f32x4){0.f, 0.f, 0.f, 0.f};

    bf16x8 ones;   // B-frag for ksum column: B[k][64]=1, rest 0 -> lanes with (l&15)==0
    #pragma unroll
    for (int j = 0; j < 8; j++) ones[j] = (short)(((l & 15) == 0) ? 0x3F80 : 0);

    const int cb = blockIdx.x * 64;               // one 64-row chunk per block
    phi_chunk<72, true>(Kp, cb, Pb, phi_lds, rc);
    #pragma unroll
    for (int ks = 0; ks < 2; ks++) {
        bf16x8 af[4];   // A = phi(K)^T: m=feature, k=krow; wave w owns feats [64w,+64)
        #pragma unroll
        for (int mt = 0; mt < 4; mt++)
            af[mt] = *(const bf16x8*)(phi_lds + (64 * w + mt * 16 + (l & 15)) * 72
                                      + ks * 32 + (l >> 4) * 8);
        const unsigned short* vb = Vb + ((size_t)((cb >> 5) + ks) * 4) * 512 + l * 8;
        bf16x8 bf4[4];
        #pragma unroll
        for (int nt = 0; nt < 4; nt++) bf4[nt] = *(const bf16x8*)(vb + nt * 512);
        #pragma unroll
        for (int mt = 0; mt < 4; mt++) {
            #pragma unroll
            for (int nt = 0; nt < 4; nt++)
                acc[mt][nt] = __builtin_amdgcn_mfma_f32_16x16x32_bf16(af[mt], bf4[nt], acc[mt][nt], 0, 0, 0);
            acc[mt][4] = __builtin_amdgcn_mfma_f32_16x16x32_bf16(af[mt], ones, acc[mt][4], 0, 0, 0);
        }
    }
    // accumulate into Zf via HW f32 atomics; rotate order by block to spread contention;
    // skip always-zero pad cols (nt==4, (l&15)!=0)
    #pragma unroll
    for (int mti = 0; mti < 4; mti++) {
        const int mt = (mti + blockIdx.x) & 3;
        #pragma unroll
        for (int nt = 0; nt < 5; nt++) {
            if (nt == 4 && (l & 15) != 0) continue;
            #pragma unroll
            for (int reg = 0; reg < 4; reg++)
                unsafeAtomicAdd(&Zf[(64 * w + mt * 16 + (l >> 4) * 4 + reg) * 80
                                    + nt * 16 + (l & 15)], acc[mt][nt][reg]);
        }
    }
}

// ---------------- zconv: Zf (f32) -> Zb (bf16, B-frag octet layout) ----------------
// Zb element (m,n) at ushort ((m>>3)*80 + n)*8 + (m&7); col 64 = ksum.
__global__ __launch_bounds__(256)
void zconv_kernel(const float* __restrict__ Zf, unsigned short* __restrict__ Zb)
{
    const int idx = blockIdx.x * 256 + threadIdx.x;
    const int m = idx / 80, n = idx - m * 80;
    Zb[((m >> 3) * 80 + n) * 8 + (m & 7)] = f2bf(Zf[idx]);
}

// ---------------- q_out: out = normalize( phi(Q) @ Zb ) ----------------
__global__ __launch_bounds__(256, 4)
void q_out_kernel(const float* __restrict__ Q, const unsigned short* __restrict__ Pb,
                  const unsigned short* __restrict__ Zb, float* __restrict__ out)
{
    __shared__ __align__(16) unsigned short phi_lds[64 * 272];   // [row][feat], padded
    __shared__ __align__(16) float rc[64];
    const int t = threadIdx.x, l = t & 63, w = t >> 6;
    const int base = blockIdx.x * 64;

    phi_chunk<272, false>(Q, base, Pb, phi_lds, rc);

    f32x4 acc[5];
    #pragma unroll
    for (int nt = 0; nt < 5; nt++) acc[nt] = (f32x4){0.f, 0.f, 0.f, 0.f};

    #pragma unroll
    for (int ks = 0; ks < 8; ks++) {
        // A = phi(Q): m = qrow (wave w rows 16w..+16), k = feature
        bf16x8 a = *(const bf16x8*)(phi_lds + (16 * w + (l & 15)) * 272 + ks * 32 + (l >> 4) * 8);
        #pragma unroll
        for (int nt = 0; nt < 5; nt++) {
            bf16x8 b = *(const bf16x8*)(Zb + ((ks * 4 + (l >> 4)) * 80 + nt * 16 + (l & 15)) * 8);
            acc[nt] = __builtin_amdgcn_mfma_f32_16x16x32_bf16(a, b, acc[nt], 0, 0, 0);
        }
    }
    // denom = output column 64 -> tile 4, lanes with (l&15)==0; broadcast within 16-group
    float inv[4];
    #pragma unroll
    for (int reg = 0; reg < 4; reg++) {
        float den = __shfl(acc[4][reg], (l & 48));
        inv[reg] = 1.0f / den;
    }
    const int row = base + 16 * w + (l >> 4) * 4;
    #pragma unroll
    for (int nt = 0; nt < 4; nt++)
        #pragma unroll
        for (int reg = 0; reg < 4; reg++)
            out[(size_t)(row + reg) * 64 + nt * 16 + (l & 15)] = acc[nt][reg] * inv[reg];
}

extern "C" void kernel_launch(void* const* d_in, const int* in_sizes, int n_in,
                              void* d_out, int out_size, void* d_ws, size_t ws_size,
                              hipStream_t stream) {
    const float* q = (const float*)d_in[0];
    const float* k = (const float*)d_in[1];
    const float* v = (const float*)d_in[2];
    const float* P = (const float*)d_in[3];
    float* out = (float*)d_out;

    unsigned short* Pb = (unsigned short*)d_ws;                          // 32 frags = 32KB
    float* Zf = (float*)((char*)d_ws + 32768);                           // 20480 f32 = 80KB
    unsigned short* Zb = (unsigned short*)((char*)d_ws + 32768 + 81920); // 20480 u16 = 40KB
    unsigned short* Vb = (unsigned short*)((char*)d_ws + 155648);        // 8192 frags = 8MB

    prep_kernel<<<2129, 256, 0, stream>>>(P, v, Pb, Vb, Zf);
    kv_atomic_kernel<<<NBKV, 256, 0, stream>>>(k, Vb, Pb, Zf);
    zconv_kernel<<<80, 256, 0, stream>>>(Zf, Zb);
    q_out_kernel<<<1024, 256, 0, stream>>>(q, Pb, Zb, out);
}

// Round 7
// 137.986 us; speedup vs baseline: 1.4711x; 1.4711x over previous
//
#include <hip/hip_runtime.h>
#include <math.h>

typedef __attribute__((ext_vector_type(8))) short bf16x8;
typedef __attribute__((ext_vector_type(4))) float f32x4;

#define RFEAT 256
#define NCOL 80                         // 64 v-cols + ksum col(64) + 15 pad
#define PARTN (RFEAT * NCOL)            // 20480 floats per partial slot
#define NBKV 512                        // kv blocks (512 threads, 128 rows each) -> 2 blocks/CU
#define NGROUP 16                       // reduce stage-1 groups (32 slots each)
#define LDK 136                         // kv phi stride: [feat][krow 0..127], pad 8

// exp2-domain: phi = ratio * exp(x.P'*sc - sc^2*||x||^2/2) = 2^( mfma(x, sc*log2e*P) + rc )
// rc = -0.5*sc^2*log2e*||x||^2 + log2(ratio);  sc = 64^-0.25 = 2^-1.5, ratio = 1/16
#define SCLOG2E 0.51006971688f          // sc * log2(e)
#define RC_COEF -0.09016844006f         // -0.5 * sc^2 * log2(e)
#define LOG2RATIO -4.0f                 // log2(1/16)

__device__ __forceinline__ unsigned short f2bf(float f) {
    union { float f; unsigned int u; } v; v.f = f;
    unsigned int r = v.u + 0x7FFFu + ((v.u >> 16) & 1u);   // RNE
    return (unsigned short)(r >> 16);
}

// ---------------- prep: Vb frags + Pb frags ----------------
// Vb frag F = s*4+nt, lane l, elem j: B[k][n] = V[s*32 + (l>>4)*8 + j][nt*16 + (l&15)].
// Pb frag f = kstep*16+nt: B[k][n] = SCLOG2E*P[n][k], n = nt*16+(l&15), k = kstep*32+(l>>4)*8+j.
__global__ __launch_bounds__(256)
void prep_kernel(const float* __restrict__ P, const float* __restrict__ V,
                 unsigned short* __restrict__ Pb, unsigned short* __restrict__ Vb)
{
    const int t = threadIdx.x, l = t & 63;
    if (blockIdx.x < 2048) {            // Vb: 2048 blocks x 4 waves = 8192 frags
        const int F = blockIdx.x * 4 + (t >> 6);
        const float* src = V + (size_t)((F >> 2) * 32 + (l >> 4) * 8) * 64 + (F & 3) * 16 + (l & 15);
        bf16x8 fr;
        #pragma unroll
        for (int j = 0; j < 8; j++) fr[j] = (short)f2bf(src[j * 64]);
        *(bf16x8*)(Vb + (size_t)F * 512 + l * 8) = fr;
        return;
    }
    // Pb (one block, 4 waves x 8 frags)
    const int g = t >> 6;
    for (int f = g * 8; f < g * 8 + 8; f++) {
        const int kstep = f >> 4, nt = f & 15;
        const float* src = P + (nt * 16 + (l & 15)) * 64 + kstep * 32 + (l >> 4) * 8;
        bf16x8 frag;
        #pragma unroll
        for (int j = 0; j < 8; j++) frag[j] = (short)f2bf(SCLOG2E * src[j]);
        *(bf16x8*)(Pb + f * 512 + l * 8) = frag;
    }
}

// ---------------- phi of a 128-row chunk -> LDS (bf16), 8 waves ----------------
// Layout: phi_lds[feat*LDK + krow], krow 0..127. Wave w owns rows [16w, +16).
__device__ __forceinline__ void phi_chunk8(const float* __restrict__ X, int chunkBase,
                                           const unsigned short* __restrict__ Pb,
                                           unsigned short* phi_lds, float* rc)
{
    const int t = threadIdx.x, l = t & 63, w = t >> 6;
    if (t < 128) {   // per-row constant (exp2 domain)
        const float4* xr = (const float4*)(X + (size_t)(chunkBase + t) * 64);
        float s0 = 0.f, s1 = 0.f;
        #pragma unroll
        for (int j = 0; j < 16; j += 2) {
            float4 a = xr[j];     s0 += a.x*a.x + a.y*a.y + a.z*a.z + a.w*a.w;
            float4 b = xr[j + 1]; s1 += b.x*b.x + b.y*b.y + b.z*b.z + b.w*b.w;
        }
        rc[t] = RC_COEF * (s0 + s1) + LOG2RATIO;
    }
    // A-frags: wave w owns rows [chunkBase+16w, +16); m = l&15, k = (l>>4)*8 + j (+32)
    const float* ar = X + (size_t)(chunkBase + 16 * w + (l & 15)) * 64 + (l >> 4) * 8;
    bf16x8 a0, a1;
    #pragma unroll
    for (int j = 0; j < 8; j++) a0[j] = (short)f2bf(ar[j]);
    #pragma unroll
    for (int j = 0; j < 8; j++) a1[j] = (short)f2bf(ar[32 + j]);
    __syncthreads();   // rc ready
    const float4 rcv = *(const float4*)(rc + 16 * w + 4 * (l >> 4));   // rc rows for D regs 0..3
    #pragma unroll
    for (int nt = 0; nt < 16; nt++) {
        bf16x8 b0 = *(const bf16x8*)(Pb + nt * 512 + l * 8);
        bf16x8 b1 = *(const bf16x8*)(Pb + (16 + nt) * 512 + l * 8);
        f32x4 acc = (f32x4){rcv.x, rcv.y, rcv.z, rcv.w};   // C-in = rc (free add)
        acc = __builtin_amdgcn_mfma_f32_16x16x32_bf16(a0, b0, acc, 0, 0, 0);
        acc = __builtin_amdgcn_mfma_f32_16x16x32_bf16(a1, b1, acc, 0, 0, 0);
        float p0 = __builtin_amdgcn_exp2f(acc[0]);
        float p1 = __builtin_amdgcn_exp2f(acc[1]);
        float p2 = __builtin_amdgcn_exp2f(acc[2]);
        float p3 = __builtin_amdgcn_exp2f(acc[3]);
        const int col = nt * 16 + (l & 15);   // feature
        unsigned int w0 = (unsigned int)f2bf(p0) | ((unsigned int)f2bf(p1) << 16);
        unsigned int w1 = (unsigned int)f2bf(p2) | ((unsigned int)f2bf(p3) << 16);
        // rows 16w + 4*(l>>4) + 0..3 contiguous -> 2 packed u32 writes
        unsigned int* dst = (unsigned int*)(phi_lds + col * LDK + 16 * w + 4 * (l >> 4));
        dst[0] = w0;
        dst[1] = w1;
    }
    __syncthreads();
}

// ---------------- kv: partials[blk] = phi(K)^T @ [V | 1] over this block's 128 rows ----------------
__global__ __launch_bounds__(512, 4)
void kv_kernel(const float* __restrict__ Kp, const unsigned short* __restrict__ Vb,
               const unsigned short* __restrict__ Pb, float* __restrict__ partials)
{
    __shared__ __align__(16) unsigned short phi_lds[RFEAT * LDK];   // [feat][krow], 69.6KB
    __shared__ __align__(16) float rc[128];
    const int t = threadIdx.x, l = t & 63, w = t >> 6;   // w in [0,8)

    f32x4 acc[2][5];
    #pragma unroll
    for (int mt = 0; mt < 2; mt++)
        #pragma unroll
        for (int nt = 0; nt < 5; nt++) acc[mt][nt] = (f32x4){0.f, 0.f, 0.f, 0.f};

    bf16x8 ones;   // B-frag for ksum column: B[k][64]=1, rest 0 -> lanes with (l&15)==0
    #pragma unroll
    for (int j = 0; j < 8; j++) ones[j] = (short)(((l & 15) == 0) ? 0x3F80 : 0);

    const int cb = blockIdx.x * 128;              // one 128-row chunk per block
    phi_chunk8(Kp, cb, Pb, phi_lds, rc);

    #pragma unroll
    for (int ks = 0; ks < 4; ks++) {              // 4 k-steps of 32 krows
        bf16x8 af[2];   // A = phi(K)^T: m=feature, k=krow; wave w owns feats [32w,+32)
        #pragma unroll
        for (int mt = 0; mt < 2; mt++)
            af[mt] = *(const bf16x8*)(phi_lds + (32 * w + mt * 16 + (l & 15)) * LDK
                                      + ks * 32 + (l >> 4) * 8);
        // B = V frags, pre-converted: frag F = ((cb>>5)+ks)*4 + nt
        const unsigned short* vb = Vb + ((size_t)((cb >> 5) + ks) * 4) * 512 + l * 8;
        bf16x8 bf4[4];
        #pragma unroll
        for (int nt = 0; nt < 4; nt++) bf4[nt] = *(const bf16x8*)(vb + nt * 512);
        #pragma unroll
        for (int mt = 0; mt < 2; mt++) {
            #pragma unroll
            for (int nt = 0; nt < 4; nt++)
                acc[mt][nt] = __builtin_amdgcn_mfma_f32_16x16x32_bf16(af[mt], bf4[nt], acc[mt][nt], 0, 0, 0);
            acc[mt][4] = __builtin_amdgcn_mfma_f32_16x16x32_bf16(af[mt], ones, acc[mt][4], 0, 0, 0);
        }
    }
    float* slot = partials + (size_t)blockIdx.x * PARTN;
    #pragma unroll
    for (int mt = 0; mt < 2; mt++)
        #pragma unroll
        for (int nt = 0; nt < 5; nt++)
            #pragma unroll
            for (int reg = 0; reg < 4; reg++)
                slot[(32 * w + mt * 16 + (l >> 4) * 4 + reg) * 80 + nt * 16 + (l & 15)] = acc[mt][nt][reg];
}

// ---------------- reduce stage 1: sum 32 slots -> p2[g][20480] ----------------
__global__ __launch_bounds__(256)
void reduce1_kernel(const float* __restrict__ partials, float* __restrict__ p2,
                    int slotsPerGroup)
{
    const int idx = blockIdx.x * 256 + threadIdx.x;   // 80*256 == 20480 exactly
    const int g = blockIdx.y;
    const float* base = partials + (size_t)g * slotsPerGroup * PARTN + idx;
    float s0 = 0.f, s1 = 0.f, s2 = 0.f, s3 = 0.f;
    int b = 0;
    for (; b + 4 <= slotsPerGroup; b += 4) {
        s0 += base[(size_t)(b + 0) * PARTN];
        s1 += base[(size_t)(b + 1) * PARTN];
        s2 += base[(size_t)(b + 2) * PARTN];
        s3 += base[(size_t)(b + 3) * PARTN];
    }
    for (; b < slotsPerGroup; b++) s0 += base[(size_t)b * PARTN];
    p2[(size_t)g * PARTN + idx] = (s0 + s1) + (s2 + s3);
}

// ---------------- reduce stage 2: sum groups -> Zb (bf16, B-frag octet layout) ----------------
// Zb element (m,n) at ushort ((m>>3)*80 + n)*8 + (m&7); col 64 = ksum.
__global__ __launch_bounds__(256)
void reduce2_kernel(const float* __restrict__ p2, unsigned short* __restrict__ Zb, int ngroups)
{
    const int idx = blockIdx.x * 256 + threadIdx.x;
    float s = 0.f;
    for (int g = 0; g < ngroups; g++) s += p2[(size_t)g * PARTN + idx];
    const int m = idx / 80, n = idx - m * 80;
    Zb[((m >> 3) * 80 + n) * 8 + (m & 7)] = f2bf(s);
}

// ---------------- phi of a 64-row chunk -> LDS [row][feat] (4 waves, for q_out) ----------------
__device__ __forceinline__ void phi_chunk_q(const float* __restrict__ X, int chunkBase,
                                            const unsigned short* __restrict__ Pb,
                                            unsigned short* phi_lds, float* rc)
{
    const int t = threadIdx.x, l = t & 63, w = t >> 6;
    if (t < 64) {
        const float4* xr = (const float4*)(X + (size_t)(chunkBase + t) * 64);
        float s0 = 0.f, s1 = 0.f;
        #pragma unroll
        for (int j = 0; j < 16; j += 2) {
            float4 a = xr[j];     s0 += a.x*a.x + a.y*a.y + a.z*a.z + a.w*a.w;
            float4 b = xr[j + 1]; s1 += b.x*b.x + b.y*b.y + b.z*b.z + b.w*b.w;
        }
        rc[t] = RC_COEF * (s0 + s1) + LOG2RATIO;
    }
    const float* ar = X + (size_t)(chunkBase + 16 * w + (l & 15)) * 64 + (l >> 4) * 8;
    bf16x8 a0, a1;
    #pragma unroll
    for (int j = 0; j < 8; j++) a0[j] = (short)f2bf(ar[j]);
    #pragma unroll
    for (int j = 0; j < 8; j++) a1[j] = (short)f2bf(ar[32 + j]);
    __syncthreads();
    const float4 rcv = *(const float4*)(rc + 16 * w + 4 * (l >> 4));
    #pragma unroll
    for (int nt = 0; nt < 16; nt++) {
        bf16x8 b0 = *(const bf16x8*)(Pb + nt * 512 + l * 8);
        bf16x8 b1 = *(const bf16x8*)(Pb + (16 + nt) * 512 + l * 8);
        f32x4 acc = (f32x4){rcv.x, rcv.y, rcv.z, rcv.w};
        acc = __builtin_amdgcn_mfma_f32_16x16x32_bf16(a0, b0, acc, 0, 0, 0);
        acc = __builtin_amdgcn_mfma_f32_16x16x32_bf16(a1, b1, acc, 0, 0, 0);
        float p0 = __builtin_amdgcn_exp2f(acc[0]);
        float p1 = __builtin_amdgcn_exp2f(acc[1]);
        float p2 = __builtin_amdgcn_exp2f(acc[2]);
        float p3 = __builtin_amdgcn_exp2f(acc[3]);
        const int col = nt * 16 + (l & 15);
        unsigned int w0 = (unsigned int)f2bf(p0) | ((unsigned int)f2bf(p1) << 16);
        unsigned int w1 = (unsigned int)f2bf(p2) | ((unsigned int)f2bf(p3) << 16);
        const int rb = (16 * w + (l >> 4) * 4) * 272 + col;
        phi_lds[rb]         = (unsigned short)(w0);
        phi_lds[rb + 272]   = (unsigned short)(w0 >> 16);
        phi_lds[rb + 544]   = (unsigned short)(w1);
        phi_lds[rb + 816]   = (unsigned short)(w1 >> 16);
    }
    __syncthreads();
}

// ---------------- q_out: out = normalize( phi(Q) @ Zb ) ----------------
__global__ __launch_bounds__(256, 4)
void q_out_kernel(const float* __restrict__ Q, const unsigned short* __restrict__ Pb,
                  const unsigned short* __restrict__ Zb, float* __restrict__ out)
{
    __shared__ __align__(16) unsigned short phi_lds[64 * 272];   // [row][feat], padded
    __shared__ __align__(16) float rc[64];
    const int t = threadIdx.x, l = t & 63, w = t >> 6;
    const int base = blockIdx.x * 64;

    phi_chunk_q(Q, base, Pb, phi_lds, rc);

    f32x4 acc[5];
    #pragma unroll
    for (int nt = 0; nt < 5; nt++) acc[nt] = (f32x4){0.f, 0.f, 0.f, 0.f};

    #pragma unroll
    for (int ks = 0; ks < 8; ks++) {
        // A = phi(Q): m = qrow (wave w rows 16w..+16), k = feature
        bf16x8 a = *(const bf16x8*)(phi_lds + (16 * w + (l & 15)) * 272 + ks * 32 + (l >> 4) * 8);
        #pragma unroll
        for (int nt = 0; nt < 5; nt++) {
            bf16x8 b = *(const bf16x8*)(Zb + ((ks * 4 + (l >> 4)) * 80 + nt * 16 + (l & 15)) * 8);
            acc[nt] = __builtin_amdgcn_mfma_f32_16x16x32_bf16(a, b, acc[nt], 0, 0, 0);
        }
    }
    // denom = output column 64 -> tile 4, lanes with (l&15)==0; broadcast within 16-group
    float inv[4];
    #pragma unroll
    for (int reg = 0; reg < 4; reg++) {
        float den = __shfl(acc[4][reg], (l & 48));
        inv[reg] = 1.0f / den;
    }
    const int row = base + 16 * w + (l >> 4) * 4;
    #pragma unroll
    for (int nt = 0; nt < 4; nt++)
        #pragma unroll
        for (int reg = 0; reg < 4; reg++)
            out[(size_t)(row + reg) * 64 + nt * 16 + (l & 15)] = acc[nt][reg] * inv[reg];
}

extern "C" void kernel_launch(void* const* d_in, const int* in_sizes, int n_in,
                              void* d_out, int out_size, void* d_ws, size_t ws_size,
                              hipStream_t stream) {
    const float* q = (const float*)d_in[0];
    const float* k = (const float*)d_in[1];
    const float* v = (const float*)d_in[2];
    const float* P = (const float*)d_in[3];
    float* out = (float*)d_out;

    unsigned short* Pb = (unsigned short*)d_ws;                  // 32 frags * 1KB = 32KB
    unsigned short* Zb = Pb + 32 * 512;                          // 20480 ushorts = 40KB
    unsigned short* Vb = (unsigned short*)((char*)d_ws + 73728); // 8192 frags * 1KB = 8MB
    float* p2 = (float*)((char*)d_ws + 73728 + 8388608);         // NGROUP*PARTN*4 = 1.3MB
    float* partials = p2 + (size_t)NGROUP * PARTN;               // NBKV*PARTN*4 = 42MB

    prep_kernel<<<2049, 256, 0, stream>>>(P, v, Pb, Vb);
    kv_kernel<<<NBKV, 512, 0, stream>>>(k, Vb, Pb, partials);
    reduce1_kernel<<<dim3(80, NGROUP), 256, 0, stream>>>(partials, p2, 32);
    reduce2_kernel<<<80, 256, 0, stream>>>(p2, Zb, NGROUP);
    q_out_kernel<<<1024, 256, 0, stream>>>(q, Pb, Zb, out);
}

// Round 8
// 130.347 us; speedup vs baseline: 1.5573x; 1.0586x over previous
//
#include <hip/hip_runtime.h>
#include <math.h>

typedef __attribute__((ext_vector_type(8))) short bf16x8;
typedef __attribute__((ext_vector_type(4))) float f32x4;

#define RFEAT 256
#define NBKV 512                        // kv blocks (512 threads, 128 rows each) -> 2 blocks/CU
#define LDK 136                         // kv phi stride: [feat][krow 0..127], pad 8
#define PCOL 66                         // partial cols: 64 v + ksum(64) + 1 pad
#define PARTU (128 * PCOL)              // 8448 u32 per slot (128 feat-pairs x 66 cols)
#define NGRP 8                          // reduceA groups (64 slots each)

// exp2-domain: phi = ratio * exp(x.P'*sc - sc^2*||x||^2/2) = 2^( mfma(x, sc*log2e*P) + rc )
// rc = -0.5*sc^2*log2e*||x||^2 + log2(ratio);  sc = 64^-0.25 = 2^-1.5, ratio = 1/16
#define SCLOG2E 0.51006971688f          // sc * log2(e)
#define RC_COEF -0.09016844006f         // -0.5 * sc^2 * log2(e)
#define LOG2RATIO -4.0f                 // log2(1/16)

__device__ __forceinline__ unsigned short f2bf(float f) {
    union { float f; unsigned int u; } v; v.f = f;
    unsigned int r = v.u + 0x7FFFu + ((v.u >> 16) & 1u);   // RNE
    return (unsigned short)(r >> 16);
}
__device__ __forceinline__ unsigned int pack2bf(float lo, float hi) {
    return (unsigned int)f2bf(lo) | ((unsigned int)f2bf(hi) << 16);
}
__device__ __forceinline__ float bf2f(unsigned int bits16) {   // low 16 bits -> f32
    union { unsigned int u; float f; } v; v.u = bits16 << 16; return v.f;
}

// ---------------- prep: Vb frags + Pb frags ----------------
// Vb frag F = s*4+nt, lane l, elem j: B[k][n] = V[s*32 + (l>>4)*8 + j][nt*16 + (l&15)].
// Pb frag f = kstep*16+nt: B[k][n] = SCLOG2E*P[n][k], n = nt*16+(l&15), k = kstep*32+(l>>4)*8+j.
__global__ __launch_bounds__(256)
void prep_kernel(const float* __restrict__ P, const float* __restrict__ V,
                 unsigned short* __restrict__ Pb, unsigned short* __restrict__ Vb)
{
    const int t = threadIdx.x, l = t & 63;
    if (blockIdx.x < 2048) {            // Vb: 2048 blocks x 4 waves = 8192 frags
        const int F = blockIdx.x * 4 + (t >> 6);
        const float* src = V + (size_t)((F >> 2) * 32 + (l >> 4) * 8) * 64 + (F & 3) * 16 + (l & 15);
        bf16x8 fr;
        #pragma unroll
        for (int j = 0; j < 8; j++) fr[j] = (short)f2bf(src[j * 64]);
        *(bf16x8*)(Vb + (size_t)F * 512 + l * 8) = fr;
        return;
    }
    // Pb (one block, 4 waves x 8 frags)
    const int g = t >> 6;
    for (int f = g * 8; f < g * 8 + 8; f++) {
        const int kstep = f >> 4, nt = f & 15;
        const float* src = P + (nt * 16 + (l & 15)) * 64 + kstep * 32 + (l >> 4) * 8;
        bf16x8 frag;
        #pragma unroll
        for (int j = 0; j < 8; j++) frag[j] = (short)f2bf(SCLOG2E * src[j]);
        *(bf16x8*)(Pb + f * 512 + l * 8) = frag;
    }
}

// ---------------- phi of a 128-row chunk -> LDS (bf16), 8 waves ----------------
// Layout: phi_lds[feat*LDK + krow], krow 0..127. Wave w owns rows [16w, +16).
__device__ __forceinline__ void phi_chunk8(const float* __restrict__ X, int chunkBase,
                                           const unsigned short* __restrict__ Pb,
                                           unsigned short* phi_lds, float* rc)
{
    const int t = threadIdx.x, l = t & 63, w = t >> 6;
    if (t < 128) {   // per-row constant (exp2 domain)
        const float4* xr = (const float4*)(X + (size_t)(chunkBase + t) * 64);
        float s0 = 0.f, s1 = 0.f;
        #pragma unroll
        for (int j = 0; j < 16; j += 2) {
            float4 a = xr[j];     s0 += a.x*a.x + a.y*a.y + a.z*a.z + a.w*a.w;
            float4 b = xr[j + 1]; s1 += b.x*b.x + b.y*b.y + b.z*b.z + b.w*b.w;
        }
        rc[t] = RC_COEF * (s0 + s1) + LOG2RATIO;
    }
    // A-frags: wave w owns rows [chunkBase+16w, +16); m = l&15, k = (l>>4)*8 + j (+32)
    const float* ar = X + (size_t)(chunkBase + 16 * w + (l & 15)) * 64 + (l >> 4) * 8;
    bf16x8 a0, a1;
    #pragma unroll
    for (int j = 0; j < 8; j++) a0[j] = (short)f2bf(ar[j]);
    #pragma unroll
    for (int j = 0; j < 8; j++) a1[j] = (short)f2bf(ar[32 + j]);
    __syncthreads();   // rc ready
    const float4 rcv = *(const float4*)(rc + 16 * w + 4 * (l >> 4));   // rc rows for D regs 0..3
    #pragma unroll
    for (int nt = 0; nt < 16; nt++) {
        bf16x8 b0 = *(const bf16x8*)(Pb + nt * 512 + l * 8);
        bf16x8 b1 = *(const bf16x8*)(Pb + (16 + nt) * 512 + l * 8);
        f32x4 acc = (f32x4){rcv.x, rcv.y, rcv.z, rcv.w};   // C-in = rc (free add)
        acc = __builtin_amdgcn_mfma_f32_16x16x32_bf16(a0, b0, acc, 0, 0, 0);
        acc = __builtin_amdgcn_mfma_f32_16x16x32_bf16(a1, b1, acc, 0, 0, 0);
        float p0 = __builtin_amdgcn_exp2f(acc[0]);
        float p1 = __builtin_amdgcn_exp2f(acc[1]);
        float p2 = __builtin_amdgcn_exp2f(acc[2]);
        float p3 = __builtin_amdgcn_exp2f(acc[3]);
        const int col = nt * 16 + (l & 15);   // feature
        unsigned int w0 = pack2bf(p0, p1);
        unsigned int w1 = pack2bf(p2, p3);
        // rows 16w + 4*(l>>4) + 0..3 contiguous -> 2 packed u32 writes
        unsigned int* dst = (unsigned int*)(phi_lds + col * LDK + 16 * w + 4 * (l >> 4));
        dst[0] = w0;
        dst[1] = w1;
    }
    __syncthreads();
}

// ---------------- kv: partials[blk] = phi(K)^T @ [V | 1], bf16-packed output ----------------
__global__ __launch_bounds__(512, 4)
void kv_kernel(const float* __restrict__ Kp, const unsigned short* __restrict__ Vb,
               const unsigned short* __restrict__ Pb, unsigned int* __restrict__ partials)
{
    __shared__ __align__(16) unsigned short phi_lds[RFEAT * LDK];   // [feat][krow], 69.6KB
    __shared__ __align__(16) float rc[128];
    const int t = threadIdx.x, l = t & 63, w = t >> 6;   // w in [0,8)

    f32x4 acc[2][5];
    #pragma unroll
    for (int mt = 0; mt < 2; mt++)
        #pragma unroll
        for (int nt = 0; nt < 5; nt++) acc[mt][nt] = (f32x4){0.f, 0.f, 0.f, 0.f};

    bf16x8 ones;   // B-frag for ksum column: B[k][64]=1, rest 0 -> lanes with (l&15)==0
    #pragma unroll
    for (int j = 0; j < 8; j++) ones[j] = (short)(((l & 15) == 0) ? 0x3F80 : 0);

    const int cb = blockIdx.x * 128;              // one 128-row chunk per block
    phi_chunk8(Kp, cb, Pb, phi_lds, rc);

    #pragma unroll
    for (int ks = 0; ks < 4; ks++) {              // 4 k-steps of 32 krows
        bf16x8 af[2];   // A = phi(K)^T: m=feature, k=krow; wave w owns feats [32w,+32)
        #pragma unroll
        for (int mt = 0; mt < 2; mt++)
            af[mt] = *(const bf16x8*)(phi_lds + (32 * w + mt * 16 + (l & 15)) * LDK
                                      + ks * 32 + (l >> 4) * 8);
        const unsigned short* vb = Vb + ((size_t)((cb >> 5) + ks) * 4) * 512 + l * 8;
        bf16x8 bf4[4];
        #pragma unroll
        for (int nt = 0; nt < 4; nt++) bf4[nt] = *(const bf16x8*)(vb + nt * 512);
        #pragma unroll
        for (int mt = 0; mt < 2; mt++) {
            #pragma unroll
            for (int nt = 0; nt < 4; nt++)
                acc[mt][nt] = __builtin_amdgcn_mfma_f32_16x16x32_bf16(af[mt], bf4[nt], acc[mt][nt], 0, 0, 0);
            acc[mt][4] = __builtin_amdgcn_mfma_f32_16x16x32_bf16(af[mt], ones, acc[mt][4], 0, 0, 0);
        }
    }
    // partials slot: u32 word at [featpair][col], featpair = feat>>1, stride PCOL
    unsigned int* slot = partials + (size_t)blockIdx.x * PARTU;
    #pragma unroll
    for (int mt = 0; mt < 2; mt++) {
        const int fpb = 16 * w + mt * 8 + ((l >> 4) << 1);   // feat-pair row of regs 0,1
        #pragma unroll
        for (int nt = 0; nt < 5; nt++) {
            if (nt == 4 && (l & 15) != 0) continue;
            const int col = nt * 16 + (l & 15);              // nt==4 -> col 64 (ksum)
            slot[fpb * PCOL + col]       = pack2bf(acc[mt][nt][0], acc[mt][nt][1]);
            slot[(fpb + 1) * PCOL + col] = pack2bf(acc[mt][nt][2], acc[mt][nt][3]);
        }
    }
}

// ---------------- reduceA: sum 64 slots (bf16 pairs, f32 accum) -> p2[g][8448] float2 ----------------
__global__ __launch_bounds__(256)
void reduceA_kernel(const unsigned int* __restrict__ partials, float2* __restrict__ p2)
{
    const int idx = blockIdx.x * 256 + threadIdx.x;   // 33*256 == 8448 exactly
    const int g = blockIdx.y;
    const unsigned int* base = partials + (size_t)g * 64 * PARTU + idx;
    float lo0 = 0.f, hi0 = 0.f, lo1 = 0.f, hi1 = 0.f;
    #pragma unroll 4
    for (int s = 0; s < 64; s += 2) {
        unsigned int u0 = base[(size_t)s * PARTU];
        unsigned int u1 = base[(size_t)(s + 1) * PARTU];
        lo0 += bf2f(u0 & 0xFFFFu); hi0 += bf2f(u0 >> 16);
        lo1 += bf2f(u1 & 0xFFFFu); hi1 += bf2f(u1 >> 16);
    }
    p2[(size_t)g * PARTU + idx] = make_float2(lo0 + lo1, hi0 + hi1);
}

// ---------------- reduceB: sum groups -> Zb (bf16, B-frag octet layout) ----------------
// Zb element (m,n) at ushort ((m>>3)*80 + n)*8 + (m&7); col 64 = ksum.
__global__ __launch_bounds__(256)
void reduceB_kernel(const float2* __restrict__ p2, unsigned short* __restrict__ Zb)
{
    const int idx = blockIdx.x * 256 + threadIdx.x;   // 0..8447
    float sLo = 0.f, sHi = 0.f;
    #pragma unroll
    for (int g = 0; g < NGRP; g++) {
        float2 v = p2[(size_t)g * PARTU + idx];
        sLo += v.x; sHi += v.y;
    }
    const int fp = idx / PCOL, col = idx - fp * PCOL;
    if (col >= 65) return;               // pad col
    const int m0 = 2 * fp, m1 = m0 + 1;
    Zb[((m0 >> 3) * 80 + col) * 8 + (m0 & 7)] = f2bf(sLo);
    Zb[((m1 >> 3) * 80 + col) * 8 + (m1 & 7)] = f2bf(sHi);
}

// ---------------- phi of a 64-row chunk -> LDS [row][feat] (4 waves, for q_out) ----------------
__device__ __forceinline__ void phi_chunk_q(const float* __restrict__ X, int chunkBase,
                                            const unsigned short* __restrict__ Pb,
                                            unsigned short* phi_lds, float* rc)
{
    const int t = threadIdx.x, l = t & 63, w = t >> 6;
    if (t < 64) {
        const float4* xr = (const float4*)(X + (size_t)(chunkBase + t) * 64);
        float s0 = 0.f, s1 = 0.f;
        #pragma unroll
        for (int j = 0; j < 16; j += 2) {
            float4 a = xr[j];     s0 += a.x*a.x + a.y*a.y + a.z*a.z + a.w*a.w;
            float4 b = xr[j + 1]; s1 += b.x*b.x + b.y*b.y + b.z*b.z + b.w*b.w;
        }
        rc[t] = RC_COEF * (s0 + s1) + LOG2RATIO;
    }
    const float* ar = X + (size_t)(chunkBase + 16 * w + (l & 15)) * 64 + (l >> 4) * 8;
    bf16x8 a0, a1;
    #pragma unroll
    for (int j = 0; j < 8; j++) a0[j] = (short)f2bf(ar[j]);
    #pragma unroll
    for (int j = 0; j < 8; j++) a1[j] = (short)f2bf(ar[32 + j]);
    __syncthreads();
    const float4 rcv = *(const float4*)(rc + 16 * w + 4 * (l >> 4));
    #pragma unroll
    for (int nt = 0; nt < 16; nt++) {
        bf16x8 b0 = *(const bf16x8*)(Pb + nt * 512 + l * 8);
        bf16x8 b1 = *(const bf16x8*)(Pb + (16 + nt) * 512 + l * 8);
        f32x4 acc = (f32x4){rcv.x, rcv.y, rcv.z, rcv.w};
        acc = __builtin_amdgcn_mfma_f32_16x16x32_bf16(a0, b0, acc, 0, 0, 0);
        acc = __builtin_amdgcn_mfma_f32_16x16x32_bf16(a1, b1, acc, 0, 0, 0);
        float p0 = __builtin_amdgcn_exp2f(acc[0]);
        float p1 = __builtin_amdgcn_exp2f(acc[1]);
        float p2 = __builtin_amdgcn_exp2f(acc[2]);
        float p3 = __builtin_amdgcn_exp2f(acc[3]);
        const int col = nt * 16 + (l & 15);
        unsigned int w0 = pack2bf(p0, p1);
        unsigned int w1 = pack2bf(p2, p3);
        const int rb = (16 * w + (l >> 4) * 4) * 272 + col;
        phi_lds[rb]         = (unsigned short)(w0);
        phi_lds[rb + 272]   = (unsigned short)(w0 >> 16);
        phi_lds[rb + 544]   = (unsigned short)(w1);
        phi_lds[rb + 816]   = (unsigned short)(w1 >> 16);
    }
    __syncthreads();
}

// ---------------- q_out: out = normalize( phi(Q) @ Zb ) ----------------
__global__ __launch_bounds__(256, 4)
void q_out_kernel(const float* __restrict__ Q, const unsigned short* __restrict__ Pb,
                  const unsigned short* __restrict__ Zb, float* __restrict__ out)
{
    __shared__ __align__(16) unsigned short phi_lds[64 * 272];   // [row][feat], padded
    __shared__ __align__(16) float rc[64];
    const int t = threadIdx.x, l = t & 63, w = t >> 6;
    const int base = blockIdx.x * 64;

    phi_chunk_q(Q, base, Pb, phi_lds, rc);

    f32x4 acc[5];
    #pragma unroll
    for (int nt = 0; nt < 5; nt++) acc[nt] = (f32x4){0.f, 0.f, 0.f, 0.f};

    #pragma unroll
    for (int ks = 0; ks < 8; ks++) {
        // A = phi(Q): m = qrow (wave w rows 16w..+16), k = feature
        bf16x8 a = *(const bf16x8*)(phi_lds + (16 * w + (l & 15)) * 272 + ks * 32 + (l >> 4) * 8);
        #pragma unroll
        for (int nt = 0; nt < 5; nt++) {
            bf16x8 b = *(const bf16x8*)(Zb + ((ks * 4 + (l >> 4)) * 80 + nt * 16 + (l & 15)) * 8);
            acc[nt] = __builtin_amdgcn_mfma_f32_16x16x32_bf16(a, b, acc[nt], 0, 0, 0);
        }
    }
    // denom = output column 64 -> tile 4, lanes with (l&15)==0; broadcast within 16-group
    float inv[4];
    #pragma unroll
    for (int reg = 0; reg < 4; reg++) {
        float den = __shfl(acc[4][reg], (l & 48));
        inv[reg] = 1.0f / den;
    }
    const int row = base + 16 * w + (l >> 4) * 4;
    #pragma unroll
    for (int nt = 0; nt < 4; nt++)
        #pragma unroll
        for (int reg = 0; reg < 4; reg++)
            out[(size_t)(row + reg) * 64 + nt * 16 + (l & 15)] = acc[nt][reg] * inv[reg];
}

extern "C" void kernel_launch(void* const* d_in, const int* in_sizes, int n_in,
                              void* d_out, int out_size, void* d_ws, size_t ws_size,
                              hipStream_t stream) {
    const float* q = (const float*)d_in[0];
    const float* k = (const float*)d_in[1];
    const float* v = (const float*)d_in[2];
    const float* P = (const float*)d_in[3];
    float* out = (float*)d_out;

    unsigned short* Pb = (unsigned short*)d_ws;                      // 32 frags = 32KB
    unsigned short* Zb = Pb + 32 * 512;                              // 20480 u16 = 40KB
    float2* p2 = (float2*)((char*)d_ws + 73728);                     // 8*8448*8 = 540.7KB
    unsigned short* Vb = (unsigned short*)((char*)d_ws + 73728 + 540672);  // 8MB
    unsigned int* partials = (unsigned int*)((char*)d_ws + 73728 + 540672 + 8388608); // 17.3MB

    prep_kernel<<<2049, 256, 0, stream>>>(P, v, Pb, Vb);
    kv_kernel<<<NBKV, 512, 0, stream>>>(k, Vb, Pb, partials);
    reduceA_kernel<<<dim3(33, NGRP), 256, 0, stream>>>(partials, p2);
    reduceB_kernel<<<33, 256, 0, stream>>>(p2, Zb);
    q_out_kernel<<<1024, 256, 0, stream>>>(q, Pb, Zb, out);
}

// Round 10
// 129.278 us; speedup vs baseline: 1.5701x; 1.0083x over previous
//
#include <hip/hip_runtime.h>
#include <math.h>

typedef __attribute__((ext_vector_type(8))) short bf16x8;
typedef __attribute__((ext_vector_type(4))) float f32x4;

#define RFEAT 256
#define NBKV 512                        // kv blocks (512 threads, 128 rows each) -> 2 blocks/CU
#define LDK 136                         // kv phi stride: [feat][krow 0..127], pad 8
#define PCOL 66                         // partial cols: 64 v + ksum(64) + 1 pad
#define PARTU (128 * PCOL)              // 8448 u32 per slot (128 feat-pairs x 66 cols)
#define NGRP 8                          // reduceA groups (64 slots each)

// exp2-domain: phi = ratio * exp(x.P'*sc - sc^2*||x||^2/2) = 2^( mfma(x, sc*log2e*P) + rc )
// rc = -0.5*sc^2*log2e*||x||^2 + log2(ratio);  sc = 64^-0.25 = 2^-1.5, ratio = 1/16
#define SCLOG2E 0.51006971688f          // sc * log2(e)
#define RC_COEF -0.09016844006f         // -0.5 * sc^2 * log2(e)
#define LOG2RATIO -4.0f                 // log2(1/16)

__device__ __forceinline__ unsigned short f2bf(float f) {
    union { float f; unsigned int u; } v; v.f = f;
    unsigned int r = v.u + 0x7FFFu + ((v.u >> 16) & 1u);   // RNE
    return (unsigned short)(r >> 16);
}
__device__ __forceinline__ unsigned int pack2bf(float lo, float hi) {
    return (unsigned int)f2bf(lo) | ((unsigned int)f2bf(hi) << 16);
}
__device__ __forceinline__ float bf2f(unsigned int bits16) {   // low 16 bits -> f32
    union { unsigned int u; float f; } v; v.u = bits16 << 16; return v.f;
}

// ---------------- prep_pb: Pb frags (1 block) ----------------
// Pb frag f = kstep*16+nt: B[k][n] = SCLOG2E*P[n][k], n = nt*16+(l&15), k = kstep*32+(l>>4)*8+j.
__global__ __launch_bounds__(256)
void prep_pb_kernel(const float* __restrict__ P, unsigned short* __restrict__ Pb)
{
    const int t = threadIdx.x, l = t & 63, g = t >> 6;
    for (int f = g * 8; f < g * 8 + 8; f++) {
        const int kstep = f >> 4, nt = f & 15;
        const float* src = P + (nt * 16 + (l & 15)) * 64 + kstep * 32 + (l >> 4) * 8;
        bf16x8 frag;
        #pragma unroll
        for (int j = 0; j < 8; j++) frag[j] = (short)f2bf(SCLOG2E * src[j]);
        *(bf16x8*)(Pb + f * 512 + l * 8) = frag;
    }
}

// ---------------- phi of a 128-row chunk -> LDS (bf16), 8 waves ----------------
// Layout: phi_lds[feat*LDK + krow], krow 0..127. Wave w owns rows [16w, +16).
__device__ __forceinline__ void phi_chunk8(const float* __restrict__ X, int chunkBase,
                                           const unsigned short* __restrict__ Pb,
                                           unsigned short* phi_lds, float* rc)
{
    const int t = threadIdx.x, l = t & 63, w = t >> 6;
    if (t < 128) {   // per-row constant (exp2 domain)
        const float4* xr = (const float4*)(X + (size_t)(chunkBase + t) * 64);
        float s0 = 0.f, s1 = 0.f;
        #pragma unroll
        for (int j = 0; j < 16; j += 2) {
            float4 a = xr[j];     s0 += a.x*a.x + a.y*a.y + a.z*a.z + a.w*a.w;
            float4 b = xr[j + 1]; s1 += b.x*b.x + b.y*b.y + b.z*b.z + b.w*b.w;
        }
        rc[t] = RC_COEF * (s0 + s1) + LOG2RATIO;
    }
    // A-frags: wave w owns rows [chunkBase+16w, +16); m = l&15, k = (l>>4)*8 + j (+32)
    const float* ar = X + (size_t)(chunkBase + 16 * w + (l & 15)) * 64 + (l >> 4) * 8;
    bf16x8 a0, a1;
    #pragma unroll
    for (int j = 0; j < 8; j++) a0[j] = (short)f2bf(ar[j]);
    #pragma unroll
    for (int j = 0; j < 8; j++) a1[j] = (short)f2bf(ar[32 + j]);
    __syncthreads();   // rc ready
    const float4 rcv = *(const float4*)(rc + 16 * w + 4 * (l >> 4));   // rc rows for D regs 0..3
    #pragma unroll
    for (int nt = 0; nt < 16; nt++) {
        bf16x8 b0 = *(const bf16x8*)(Pb + nt * 512 + l * 8);
        bf16x8 b1 = *(const bf16x8*)(Pb + (16 + nt) * 512 + l * 8);
        f32x4 acc = (f32x4){rcv.x, rcv.y, rcv.z, rcv.w};   // C-in = rc (free add)
        acc = __builtin_amdgcn_mfma_f32_16x16x32_bf16(a0, b0, acc, 0, 0, 0);
        acc = __builtin_amdgcn_mfma_f32_16x16x32_bf16(a1, b1, acc, 0, 0, 0);
        float p0 = __builtin_amdgcn_exp2f(acc[0]);
        float p1 = __builtin_amdgcn_exp2f(acc[1]);
        float p2 = __builtin_amdgcn_exp2f(acc[2]);
        float p3 = __builtin_amdgcn_exp2f(acc[3]);
        const int col = nt * 16 + (l & 15);   // feature
        unsigned int w0 = pack2bf(p0, p1);
        unsigned int w1 = pack2bf(p2, p3);
        // rows 16w + 4*(l>>4) + 0..3 contiguous -> 2 packed u32 writes
        unsigned int* dst = (unsigned int*)(phi_lds + col * LDK + 16 * w + 4 * (l >> 4));
        dst[0] = w0;
        dst[1] = w1;
    }
    __syncthreads();
}

// ---------------- kv: partials[blk] = phi(K)^T @ [V | 1], inline V->bf16, packed out ----------------
__global__ __launch_bounds__(512, 4)
void kv_kernel(const float* __restrict__ Kp, const float* __restrict__ V,
               const unsigned short* __restrict__ Pb, unsigned int* __restrict__ partials)
{
    __shared__ __align__(16) unsigned short phi_lds[RFEAT * LDK];   // [feat][krow], 69.6KB
    __shared__ __align__(16) float rc[128];
    const int t = threadIdx.x, l = t & 63, w = t >> 6;   // w in [0,8)

    f32x4 acc[2][5];
    #pragma unroll
    for (int mt = 0; mt < 2; mt++)
        #pragma unroll
        for (int nt = 0; nt < 5; nt++) acc[mt][nt] = (f32x4){0.f, 0.f, 0.f, 0.f};

    bf16x8 ones;   // B-frag for ksum column: B[k][64]=1, rest 0 -> lanes with (l&15)==0
    #pragma unroll
    for (int j = 0; j < 8; j++) ones[j] = (short)(((l & 15) == 0) ? 0x3F80 : 0);

    const int cb = blockIdx.x * 128;              // one 128-row chunk per block
    phi_chunk8(Kp, cb, Pb, phi_lds, rc);

    #pragma unroll
    for (int ks = 0; ks < 4; ks++) {              // 4 k-steps of 32 krows
        bf16x8 af[2];   // A = phi(K)^T: m=feature, k=krow; wave w owns feats [32w,+32)
        #pragma unroll
        for (int mt = 0; mt < 2; mt++)
            af[mt] = *(const bf16x8*)(phi_lds + (32 * w + mt * 16 + (l & 15)) * LDK
                                      + ks * 32 + (l >> 4) * 8);
        // B = V frags, converted inline: B[k][n] = V[cb + ks*32 + (l>>4)*8 + j][nt*16 + (l&15)]
        const float* vbase = V + (size_t)(cb + ks * 32 + (l >> 4) * 8) * 64 + (l & 15);
        bf16x8 bf4[4];
        #pragma unroll
        for (int nt = 0; nt < 4; nt++) {
            const float* vp = vbase + nt * 16;
            bf16x8 bb;
            #pragma unroll
            for (int j = 0; j < 8; j++) bb[j] = (short)f2bf(vp[j * 64]);
            bf4[nt] = bb;
        }
        #pragma unroll
        for (int mt = 0; mt < 2; mt++) {
            #pragma unroll
            for (int nt = 0; nt < 4; nt++)
                acc[mt][nt] = __builtin_amdgcn_mfma_f32_16x16x32_bf16(af[mt], bf4[nt], acc[mt][nt], 0, 0, 0);
            acc[mt][4] = __builtin_amdgcn_mfma_f32_16x16x32_bf16(af[mt], ones, acc[mt][4], 0, 0, 0);
        }
    }
    // partials slot: u32 word at [featpair][col], featpair = feat>>1, stride PCOL
    unsigned int* slot = partials + (size_t)blockIdx.x * PARTU;
    #pragma unroll
    for (int mt = 0; mt < 2; mt++) {
        const int fpb = 16 * w + mt * 8 + ((l >> 4) << 1);   // feat-pair row of regs 0,1
        #pragma unroll
        for (int nt = 0; nt < 5; nt++) {
            if (nt == 4 && (l & 15) != 0) continue;
            const int col = nt * 16 + (l & 15);              // nt==4 -> col 64 (ksum)
            slot[fpb * PCOL + col]       = pack2bf(acc[mt][nt][0], acc[mt][nt][1]);
            slot[(fpb + 1) * PCOL + col] = pack2bf(acc[mt][nt][2], acc[mt][nt][3]);
        }
    }
}

// ---------------- reduceA: sum 64 slots (bf16 pairs, f32 accum) -> p2[g][8448] float2 ----------------
__global__ __launch_bounds__(256)
void reduceA_kernel(const unsigned int* __restrict__ partials, float2* __restrict__ p2)
{
    const int idx = blockIdx.x * 256 + threadIdx.x;   // 33*256 == 8448 exactly
    const int g = blockIdx.y;
    const unsigned int* base = partials + (size_t)g * 64 * PARTU + idx;
    float lo0 = 0.f, hi0 = 0.f, lo1 = 0.f, hi1 = 0.f;
    #pragma unroll 4
    for (int s = 0; s < 64; s += 2) {
        unsigned int u0 = base[(size_t)s * PARTU];
        unsigned int u1 = base[(size_t)(s + 1) * PARTU];
        lo0 += bf2f(u0 & 0xFFFFu); hi0 += bf2f(u0 >> 16);
        lo1 += bf2f(u1 & 0xFFFFu); hi1 += bf2f(u1 >> 16);
    }
    p2[(size_t)g * PARTU + idx] = make_float2(lo0 + lo1, hi0 + hi1);
}

// ---------------- reduceB: sum groups -> Zb (bf16, B-frag octet layout) ----------------
// Zb element (m,n) at ushort ((m>>3)*80 + n)*8 + (m&7); col 64 = ksum.
__global__ __launch_bounds__(256)
void reduceB_kernel(const float2* __restrict__ p2, unsigned short* __restrict__ Zb)
{
    const int idx = blockIdx.x * 256 + threadIdx.x;   // 0..8447
    float sLo = 0.f, sHi = 0.f;
    #pragma unroll
    for (int g = 0; g < NGRP; g++) {
        float2 v = p2[(size_t)g * PARTU + idx];
        sLo += v.x; sHi += v.y;
    }
    const int fp = idx / PCOL, col = idx - fp * PCOL;
    if (col >= 65) return;               // pad col
    const int m0 = 2 * fp, m1 = m0 + 1;
    Zb[((m0 >> 3) * 80 + col) * 8 + (m0 & 7)] = f2bf(sLo);
    Zb[((m1 >> 3) * 80 + col) * 8 + (m1 & 7)] = f2bf(sHi);
}

// ---------------- phi of a 64-row chunk -> LDS [row][feat] (4 waves, for q_out) ----------------
__device__ __forceinline__ void phi_chunk_q(const float* __restrict__ X, int chunkBase,
                                            const unsigned short* __restrict__ Pb,
                                            unsigned short* phi_lds, float* rc)
{
    const int t = threadIdx.x, l = t & 63, w = t >> 6;
    if (t < 64) {
        const float4* xr = (const float4*)(X + (size_t)(chunkBase + t) * 64);
        float s0 = 0.f, s1 = 0.f;
        #pragma unroll
        for (int j = 0; j < 16; j += 2) {
            float4 a = xr[j];     s0 += a.x*a.x + a.y*a.y + a.z*a.z + a.w*a.w;
            float4 b = xr[j + 1]; s1 += b.x*b.x + b.y*b.y + b.z*b.z + b.w*b.w;
        }
        rc[t] = RC_COEF * (s0 + s1) + LOG2RATIO;
    }
    const float* ar = X + (size_t)(chunkBase + 16 * w + (l & 15)) * 64 + (l >> 4) * 8;
    bf16x8 a0, a1;
    #pragma unroll
    for (int j = 0; j < 8; j++) a0[j] = (short)f2bf(ar[j]);
    #pragma unroll
    for (int j = 0; j < 8; j++) a1[j] = (short)f2bf(ar[32 + j]);
    __syncthreads();
    const float4 rcv = *(const float4*)(rc + 16 * w + 4 * (l >> 4));
    #pragma unroll
    for (int nt = 0; nt < 16; nt++) {
        bf16x8 b0 = *(const bf16x8*)(Pb + nt * 512 + l * 8);
        bf16x8 b1 = *(const bf16x8*)(Pb + (16 + nt) * 512 + l * 8);
        f32x4 acc = (f32x4){rcv.x, rcv.y, rcv.z, rcv.w};
        acc = __builtin_amdgcn_mfma_f32_16x16x32_bf16(a0, b0, acc, 0, 0, 0);
        acc = __builtin_amdgcn_mfma_f32_16x16x32_bf16(a1, b1, acc, 0, 0, 0);
        float p0 = __builtin_amdgcn_exp2f(acc[0]);
        float p1 = __builtin_amdgcn_exp2f(acc[1]);
        float p2 = __builtin_amdgcn_exp2f(acc[2]);
        float p3 = __builtin_amdgcn_exp2f(acc[3]);
        const int col = nt * 16 + (l & 15);
        unsigned int w0 = pack2bf(p0, p1);
        unsigned int w1 = pack2bf(p2, p3);
        const int rb = (16 * w + (l >> 4) * 4) * 272 + col;
        phi_lds[rb]         = (unsigned short)(w0);
        phi_lds[rb + 272]   = (unsigned short)(w0 >> 16);
        phi_lds[rb + 544]   = (unsigned short)(w1);
        phi_lds[rb + 816]   = (unsigned short)(w1 >> 16);
    }
    __syncthreads();
}

// ---------------- q_out: out = normalize( phi(Q) @ Zb ) ----------------
__global__ __launch_bounds__(256, 4)
void q_out_kernel(const float* __restrict__ Q, const unsigned short* __restrict__ Pb,
                  const unsigned short* __restrict__ Zb, float* __restrict__ out)
{
    __shared__ __align__(16) unsigned short phi_lds[64 * 272];   // [row][feat], padded
    __shared__ __align__(16) float rc[64];
    const int t = threadIdx.x, l = t & 63, w = t >> 6;
    const int base = blockIdx.x * 64;

    phi_chunk_q(Q, base, Pb, phi_lds, rc);

    f32x4 acc[5];
    #pragma unroll
    for (int nt = 0; nt < 5; nt++) acc[nt] = (f32x4){0.f, 0.f, 0.f, 0.f};

    #pragma unroll
    for (int ks = 0; ks < 8; ks++) {
        // A = phi(Q): m = qrow (wave w rows 16w..+16), k = feature
        bf16x8 a = *(const bf16x8*)(phi_lds + (16 * w + (l & 15)) * 272 + ks * 32 + (l >> 4) * 8);
        #pragma unroll
        for (int nt = 0; nt < 5; nt++) {
            bf16x8 b = *(const bf16x8*)(Zb + ((ks * 4 + (l >> 4)) * 80 + nt * 16 + (l & 15)) * 8);
            acc[nt] = __builtin_amdgcn_mfma_f32_16x16x32_bf16(a, b, acc[nt], 0, 0, 0);
        }
    }
    // denom = output column 64 -> tile 4, lanes with (l&15)==0; broadcast within 16-group
    float inv[4];
    #pragma unroll
    for (int reg = 0; reg < 4; reg++) {
        float den = __shfl(acc[4][reg], (l & 48));
        inv[reg] = 1.0f / den;
    }
    const int row = base + 16 * w + (l >> 4) * 4;
    #pragma unroll
    for (int nt = 0; nt < 4; nt++)
        #pragma unroll
        for (int reg = 0; reg < 4; reg++)
            out[(size_t)(row + reg) * 64 + nt * 16 + (l & 15)] = acc[nt][reg] * inv[reg];
}

extern "C" void kernel_launch(void* const* d_in, const int* in_sizes, int n_in,
                              void* d_out, int out_size, void* d_ws, size_t ws_size,
                              hipStream_t stream) {
    const float* q = (const float*)d_in[0];
    const float* k = (const float*)d_in[1];
    const float* v = (const float*)d_in[2];
    const float* P = (const float*)d_in[3];
    float* out = (float*)d_out;

    unsigned short* Pb = (unsigned short*)d_ws;                      // 32 frags = 32KB
    unsigned short* Zb = Pb + 32 * 512;                              // 20480 u16 = 40KB
    float2* p2 = (float2*)((char*)d_ws + 73728);                     // 8*8448*8 = 540.7KB
    unsigned int* partials = (unsigned int*)((char*)d_ws + 73728 + 540672); // 512*8448*4 = 17.3MB

    prep_pb_kernel<<<1, 256, 0, stream>>>(P, Pb);
    kv_kernel<<<NBKV, 512, 0, stream>>>(k, v, Pb, partials);
    reduceA_kernel<<<dim3(33, NGRP), 256, 0, stream>>>(partials, p2);
    reduceB_kernel<<<33, 256, 0, stream>>>(p2, Zb);
    q_out_kernel<<<1024, 256, 0, stream>>>(q, Pb, Zb, out);
}

// Round 11
// 128.013 us; speedup vs baseline: 1.5857x; 1.0099x over previous
//
#include <hip/hip_runtime.h>
#include <math.h>

typedef __attribute__((ext_vector_type(8))) short bf16x8;
typedef __attribute__((ext_vector_type(4))) float f32x4;

#define RFEAT 256
#define NBKV 512                        // kv blocks (512 threads, 128 rows each) -> 2 blocks/CU
#define PCOL 66                         // partial cols: 64 v + ksum(64) + 1 pad
#define PARTU (128 * PCOL)              // 8448 u32 per slot (128 feat-pairs x 66 cols)
#define NGRP 8                          // reduceA groups (64 slots each)

// swizzled LDS offsets (u16 index): stride 128, XOR row bits 3..5 with low feat/col bits
#define PHI_OFF(feat, row) ((feat) * 128 + ((row) ^ (((feat) & 7) << 3)))
#define V_OFF(col, krow)   ((col) * 128 + ((krow) ^ (((col) & 7) << 3)))

// exp2-domain: phi = ratio * exp(x.P'*sc - sc^2*||x||^2/2) = 2^( mfma(x, sc*log2e*P) + rc )
// rc = -0.5*sc^2*log2e*||x||^2 + log2(ratio);  sc = 64^-0.25 = 2^-1.5, ratio = 1/16
#define SCLOG2E 0.51006971688f          // sc * log2(e)
#define RC_COEF -0.09016844006f         // -0.5 * sc^2 * log2(e)
#define LOG2RATIO -4.0f                 // log2(1/16)

__device__ __forceinline__ unsigned short f2bf(float f) {
    union { float f; unsigned int u; } v; v.f = f;
    unsigned int r = v.u + 0x7FFFu + ((v.u >> 16) & 1u);   // RNE
    return (unsigned short)(r >> 16);
}
__device__ __forceinline__ unsigned int pack2bf(float lo, float hi) {
    return (unsigned int)f2bf(lo) | ((unsigned int)f2bf(hi) << 16);
}
__device__ __forceinline__ float bf2f(unsigned int bits16) {   // low 16 bits -> f32
    union { unsigned int u; float f; } v; v.u = bits16 << 16; return v.f;
}

// ---------------- prep_pb: Pb frags (1 block) ----------------
// Pb frag f = kstep*16+nt: B[k][n] = SCLOG2E*P[n][k], n = nt*16+(l&15), k = kstep*32+(l>>4)*8+j.
__global__ __launch_bounds__(256)
void prep_pb_kernel(const float* __restrict__ P, unsigned short* __restrict__ Pb)
{
    const int t = threadIdx.x, l = t & 63, g = t >> 6;
    for (int f = g * 8; f < g * 8 + 8; f++) {
        const int kstep = f >> 4, nt = f & 15;
        const float* src = P + (nt * 16 + (l & 15)) * 64 + kstep * 32 + (l >> 4) * 8;
        bf16x8 frag;
        #pragma unroll
        for (int j = 0; j < 8; j++) frag[j] = (short)f2bf(SCLOG2E * src[j]);
        *(bf16x8*)(Pb + f * 512 + l * 8) = frag;
    }
}

// ---------------- phi of a 128-row chunk -> swizzled LDS (bf16), 8 waves ----------------
// phi value for (row, feat) lands at u16 index PHI_OFF(feat, row).
__device__ __forceinline__ void phi_chunk8_swz(const float* __restrict__ X, int chunkBase,
                                               const unsigned short* __restrict__ Pb,
                                               unsigned short* phi_lds, float* rc)
{
    const int t = threadIdx.x, l = t & 63, w = t >> 6;
    if (t < 128) {   // per-row constant (exp2 domain)
        const float4* xr = (const float4*)(X + (size_t)(chunkBase + t) * 64);
        float s0 = 0.f, s1 = 0.f;
        #pragma unroll
        for (int j = 0; j < 16; j += 2) {
            float4 a = xr[j];     s0 += a.x*a.x + a.y*a.y + a.z*a.z + a.w*a.w;
            float4 b = xr[j + 1]; s1 += b.x*b.x + b.y*b.y + b.z*b.z + b.w*b.w;
        }
        rc[t] = RC_COEF * (s0 + s1) + LOG2RATIO;
    }
    // A-frags: wave w owns rows [chunkBase+16w, +16); m = l&15, k = (l>>4)*8 + j (+32)
    const float* ar = X + (size_t)(chunkBase + 16 * w + (l & 15)) * 64 + (l >> 4) * 8;
    bf16x8 a0, a1;
    #pragma unroll
    for (int j = 0; j < 8; j++) a0[j] = (short)f2bf(ar[j]);
    #pragma unroll
    for (int j = 0; j < 8; j++) a1[j] = (short)f2bf(ar[32 + j]);
    __syncthreads();   // rc ready
    const float4 rcv = *(const float4*)(rc + 16 * w + 4 * (l >> 4));   // rc rows for D regs 0..3
    #pragma unroll
    for (int nt = 0; nt < 16; nt++) {
        bf16x8 b0 = *(const bf16x8*)(Pb + nt * 512 + l * 8);
        bf16x8 b1 = *(const bf16x8*)(Pb + (16 + nt) * 512 + l * 8);
        f32x4 acc = (f32x4){rcv.x, rcv.y, rcv.z, rcv.w};   // C-in = rc (free add)
        acc = __builtin_amdgcn_mfma_f32_16x16x32_bf16(a0, b0, acc, 0, 0, 0);
        acc = __builtin_amdgcn_mfma_f32_16x16x32_bf16(a1, b1, acc, 0, 0, 0);
        float p0 = __builtin_amdgcn_exp2f(acc[0]);
        float p1 = __builtin_amdgcn_exp2f(acc[1]);
        float p2 = __builtin_amdgcn_exp2f(acc[2]);
        float p3 = __builtin_amdgcn_exp2f(acc[3]);
        const int col = nt * 16 + (l & 15);   // feature
        const int r0 = 16 * w + 4 * (l >> 4); // rows r0..r0+3 (bits 0..2 intact under XOR)
        unsigned int* dst = (unsigned int*)(phi_lds + PHI_OFF(col, r0));
        dst[0] = pack2bf(p0, p1);
        dst[1] = pack2bf(p2, p3);
    }
    __syncthreads();
}

// ---------------- kv: partials[blk] = phi(K)^T @ [V | 1], V staged once in LDS ----------------
__global__ __launch_bounds__(512, 4)
void kv_kernel(const float* __restrict__ Kp, const float* __restrict__ V,
               const unsigned short* __restrict__ Pb, unsigned int* __restrict__ partials)
{
    __shared__ __align__(16) unsigned short phi_lds[RFEAT * 128];   // 64 KB, swizzled
    __shared__ __align__(16) unsigned short v_lds[64 * 128];        // 16 KB, swizzled
    float* rc = (float*)v_lds;    // 512 B alias; rc dead before V stores (after phi's final sync)
    const int t = threadIdx.x, l = t & 63, w = t >> 6;   // w in [0,8)
    const int cb = blockIdx.x * 128;              // one 128-row chunk per block

    // T14 early-issue: thread t loads V col (t&63), krows [(t>>6)*16, +16) -> regs
    const int vcol = t & 63, vr0 = (t >> 6) * 16;
    float vreg[16];
    #pragma unroll
    for (int i = 0; i < 16; i++)
        vreg[i] = V[(size_t)(cb + vr0 + i) * 64 + vcol];

    phi_chunk8_swz(Kp, cb, Pb, phi_lds, rc);      // ends with __syncthreads (rc now dead)

    // convert V -> v_lds (bf16, swizzled): 2 x b128 stores per thread
    {
        unsigned int pk[8];
        #pragma unroll
        for (int i = 0; i < 8; i++) pk[i] = pack2bf(vreg[2 * i], vreg[2 * i + 1]);
        unsigned int* d0 = (unsigned int*)(v_lds + V_OFF(vcol, vr0));
        unsigned int* d1 = (unsigned int*)(v_lds + V_OFF(vcol, vr0 + 8));
        d0[0] = pk[0]; d0[1] = pk[1]; d0[2] = pk[2]; d0[3] = pk[3];
        d1[0] = pk[4]; d1[1] = pk[5]; d1[2] = pk[6]; d1[3] = pk[7];
    }
    __syncthreads();

    f32x4 acc[2][5];
    #pragma unroll
    for (int mt = 0; mt < 2; mt++)
        #pragma unroll
        for (int nt = 0; nt < 5; nt++) acc[mt][nt] = (f32x4){0.f, 0.f, 0.f, 0.f};

    bf16x8 ones;   // B-frag for ksum column: B[k][64]=1, rest 0 -> lanes with (l&15)==0
    #pragma unroll
    for (int j = 0; j < 8; j++) ones[j] = (short)(((l & 15) == 0) ? 0x3F80 : 0);

    #pragma unroll
    for (int ks = 0; ks < 4; ks++) {              // 4 k-steps of 32 krows
        const int krow0 = ks * 32 + (l >> 4) * 8;
        bf16x8 af[2];   // A = phi(K)^T: m=feature, k=krow; wave w owns feats [32w,+32)
        #pragma unroll
        for (int mt = 0; mt < 2; mt++)
            af[mt] = *(const bf16x8*)(phi_lds + PHI_OFF(32 * w + mt * 16 + (l & 15), krow0));
        bf16x8 bf4[4];  // B = V bf16 from LDS
        #pragma unroll
        for (int nt = 0; nt < 4; nt++)
            bf4[nt] = *(const bf16x8*)(v_lds + V_OFF(nt * 16 + (l & 15), krow0));
        #pragma unroll
        for (int mt = 0; mt < 2; mt++) {
            #pragma unroll
            for (int nt = 0; nt < 4; nt++)
                acc[mt][nt] = __builtin_amdgcn_mfma_f32_16x16x32_bf16(af[mt], bf4[nt], acc[mt][nt], 0, 0, 0);
            acc[mt][4] = __builtin_amdgcn_mfma_f32_16x16x32_bf16(af[mt], ones, acc[mt][4], 0, 0, 0);
        }
    }
    // partials slot: u32 word at [featpair][col], featpair = feat>>1, stride PCOL
    unsigned int* slot = partials + (size_t)blockIdx.x * PARTU;
    #pragma unroll
    for (int mt = 0; mt < 2; mt++) {
        const int fpb = 16 * w + mt * 8 + ((l >> 4) << 1);   // feat-pair row of regs 0,1
        #pragma unroll
        for (int nt = 0; nt < 5; nt++) {
            if (nt == 4 && (l & 15) != 0) continue;
            const int col = nt * 16 + (l & 15);              // nt==4 -> col 64 (ksum)
            slot[fpb * PCOL + col]       = pack2bf(acc[mt][nt][0], acc[mt][nt][1]);
            slot[(fpb + 1) * PCOL + col] = pack2bf(acc[mt][nt][2], acc[mt][nt][3]);
        }
    }
}

// ---------------- reduceA: sum 64 slots (bf16 pairs, f32 accum) -> p2[g][8448] float2 ----------------
__global__ __launch_bounds__(256)
void reduceA_kernel(const unsigned int* __restrict__ partials, float2* __restrict__ p2)
{
    const int idx = blockIdx.x * 256 + threadIdx.x;   // 33*256 == 8448 exactly
    const int g = blockIdx.y;
    const unsigned int* base = partials + (size_t)g * 64 * PARTU + idx;
    float lo0 = 0.f, hi0 = 0.f, lo1 = 0.f, hi1 = 0.f;
    #pragma unroll 4
    for (int s = 0; s < 64; s += 2) {
        unsigned int u0 = base[(size_t)s * PARTU];
        unsigned int u1 = base[(size_t)(s + 1) * PARTU];
        lo0 += bf2f(u0 & 0xFFFFu); hi0 += bf2f(u0 >> 16);
        lo1 += bf2f(u1 & 0xFFFFu); hi1 += bf2f(u1 >> 16);
    }
    p2[(size_t)g * PARTU + idx] = make_float2(lo0 + lo1, hi0 + hi1);
}

// ---------------- reduceB: sum groups -> Zb (bf16, B-frag octet layout) ----------------
// Zb element (m,n) at ushort ((m>>3)*80 + n)*8 + (m&7); col 64 = ksum.
__global__ __launch_bounds__(256)
void reduceB_kernel(const float2* __restrict__ p2, unsigned short* __restrict__ Zb)
{
    const int idx = blockIdx.x * 256 + threadIdx.x;   // 0..8447
    float sLo = 0.f, sHi = 0.f;
    #pragma unroll
    for (int g = 0; g < NGRP; g++) {
        float2 v = p2[(size_t)g * PARTU + idx];
        sLo += v.x; sHi += v.y;
    }
    const int fp = idx / PCOL, col = idx - fp * PCOL;
    if (col >= 65) return;               // pad col
    const int m0 = 2 * fp, m1 = m0 + 1;
    Zb[((m0 >> 3) * 80 + col) * 8 + (m0 & 7)] = f2bf(sLo);
    Zb[((m1 >> 3) * 80 + col) * 8 + (m1 & 7)] = f2bf(sHi);
}

// ---------------- phi of a 64-row chunk -> LDS [row][feat] (4 waves, for q_out) ----------------
__device__ __forceinline__ void phi_chunk_q(const float* __restrict__ X, int chunkBase,
                                            const unsigned short* __restrict__ Pb,
                                            unsigned short* phi_lds, float* rc)
{
    const int t = threadIdx.x, l = t & 63, w = t >> 6;
    if (t < 64) {
        const float4* xr = (const float4*)(X + (size_t)(chunkBase + t) * 64);
        float s0 = 0.f, s1 = 0.f;
        #pragma unroll
        for (int j = 0; j < 16; j += 2) {
            float4 a = xr[j];     s0 += a.x*a.x + a.y*a.y + a.z*a.z + a.w*a.w;
            float4 b = xr[j + 1]; s1 += b.x*b.x + b.y*b.y + b.z*b.z + b.w*b.w;
        }
        rc[t] = RC_COEF * (s0 + s1) + LOG2RATIO;
    }
    const float* ar = X + (size_t)(chunkBase + 16 * w + (l & 15)) * 64 + (l >> 4) * 8;
    bf16x8 a0, a1;
    #pragma unroll
    for (int j = 0; j < 8; j++) a0[j] = (short)f2bf(ar[j]);
    #pragma unroll
    for (int j = 0; j < 8; j++) a1[j] = (short)f2bf(ar[32 + j]);
    __syncthreads();
    const float4 rcv = *(const float4*)(rc + 16 * w + 4 * (l >> 4));
    #pragma unroll
    for (int nt = 0; nt < 16; nt++) {
        bf16x8 b0 = *(const bf16x8*)(Pb + nt * 512 + l * 8);
        bf16x8 b1 = *(const bf16x8*)(Pb + (16 + nt) * 512 + l * 8);
        f32x4 acc = (f32x4){rcv.x, rcv.y, rcv.z, rcv.w};
        acc = __builtin_amdgcn_mfma_f32_16x16x32_bf16(a0, b0, acc, 0, 0, 0);
        acc = __builtin_amdgcn_mfma_f32_16x16x32_bf16(a1, b1, acc, 0, 0, 0);
        float p0 = __builtin_amdgcn_exp2f(acc[0]);
        float p1 = __builtin_amdgcn_exp2f(acc[1]);
        float p2 = __builtin_amdgcn_exp2f(acc[2]);
        float p3 = __builtin_amdgcn_exp2f(acc[3]);
        const int col = nt * 16 + (l & 15);
        unsigned int w0 = pack2bf(p0, p1);
        unsigned int w1 = pack2bf(p2, p3);
        const int rb = (16 * w + (l >> 4) * 4) * 272 + col;
        phi_lds[rb]         = (unsigned short)(w0);
        phi_lds[rb + 272]   = (unsigned short)(w0 >> 16);
        phi_lds[rb + 544]   = (unsigned short)(w1);
        phi_lds[rb + 816]   = (unsigned short)(w1 >> 16);
    }
    __syncthreads();
}

// ---------------- q_out: out = normalize( phi(Q) @ Zb ) ----------------
__global__ __launch_bounds__(256, 4)
void q_out_kernel(const float* __restrict__ Q, const unsigned short* __restrict__ Pb,
                  const unsigned short* __restrict__ Zb, float* __restrict__ out)
{
    __shared__ __align__(16) unsigned short phi_lds[64 * 272];   // [row][feat], padded
    __shared__ __align__(16) float rc[64];
    const int t = threadIdx.x, l = t & 63, w = t >> 6;
    const int base = blockIdx.x * 64;

    phi_chunk_q(Q, base, Pb, phi_lds, rc);

    f32x4 acc[5];
    #pragma unroll
    for (int nt = 0; nt < 5; nt++) acc[nt] = (f32x4){0.f, 0.f, 0.f, 0.f};

    #pragma unroll
    for (int ks = 0; ks < 8; ks++) {
        // A = phi(Q): m = qrow (wave w rows 16w..+16), k = feature
        bf16x8 a = *(const bf16x8*)(phi_lds + (16 * w + (l & 15)) * 272 + ks * 32 + (l >> 4) * 8);
        #pragma unroll
        for (int nt = 0; nt < 5; nt++) {
            bf16x8 b = *(const bf16x8*)(Zb + ((ks * 4 + (l >> 4)) * 80 + nt * 16 + (l & 15)) * 8);
            acc[nt] = __builtin_amdgcn_mfma_f32_16x16x32_bf16(a, b, acc[nt], 0, 0, 0);
        }
    }
    // denom = output column 64 -> tile 4, lanes with (l&15)==0; broadcast within 16-group
    float inv[4];
    #pragma unroll
    for (int reg = 0; reg < 4; reg++) {
        float den = __shfl(acc[4][reg], (l & 48));
        inv[reg] = 1.0f / den;
    }
    const int row = base + 16 * w + (l >> 4) * 4;
    #pragma unroll
    for (int nt = 0; nt < 4; nt++)
        #pragma unroll
        for (int reg = 0; reg < 4; reg++)
            out[(size_t)(row + reg) * 64 + nt * 16 + (l & 15)] = acc[nt][reg] * inv[reg];
}

extern "C" void kernel_launch(void* const* d_in, const int* in_sizes, int n_in,
                              void* d_out, int out_size, void* d_ws, size_t ws_size,
                              hipStream_t stream) {
    const float* q = (const float*)d_in[0];
    const float* k = (const float*)d_in[1];
    const float* v = (const float*)d_in[2];
    const float* P = (const float*)d_in[3];
    float* out = (float*)d_out;

    unsigned short* Pb = (unsigned short*)d_ws;                      // 32 frags = 32KB
    unsigned short* Zb = Pb + 32 * 512;                              // 20480 u16 = 40KB
    float2* p2 = (float2*)((char*)d_ws + 73728);                     // 8*8448*8 = 540.7KB
    unsigned int* partials = (unsigned int*)((char*)d_ws + 73728 + 540672); // 512*8448*4 = 17.3MB

    prep_pb_kernel<<<1, 256, 0, stream>>>(P, Pb);
    kv_kernel<<<NBKV, 512, 0, stream>>>(k, v, Pb, partials);
    reduceA_kernel<<<dim3(33, NGRP), 256, 0, stream>>>(partials, p2);
    reduceB_kernel<<<33, 256, 0, stream>>>(p2, Zb);
    q_out_kernel<<<1024, 256, 0, stream>>>(q, Pb, Zb, out);
}

// Round 12
// 126.103 us; speedup vs baseline: 1.6097x; 1.0151x over previous
//
#include <hip/hip_runtime.h>
#include <hip/hip_bf16.h>
#include <math.h>

typedef __attribute__((ext_vector_type(8))) short bf16x8;
typedef __attribute__((ext_vector_type(4))) float f32x4;

#define RFEAT 256
#define NBKV 512                        // kv blocks (512 threads, 128 rows each) -> 2 blocks/CU
#define PCOL 66                         // partial cols: 64 v + ksum(64) + 1 pad
#define PARTU (128 * PCOL)              // 8448 u32 per slot (128 feat-pairs x 66 cols)
#define NGRP 8                          // reduceA groups (64 slots each)
#define LDQ 264                         // q_out phi stride (u16): 132%32=4 -> 2-way reads

// swizzled LDS offsets (u16 index): stride 128, XOR row bits 3..5 with low feat/col bits
#define PHI_OFF(feat, row) ((feat) * 128 + ((row) ^ (((feat) & 7) << 3)))
#define V_OFF(col, krow)   ((col) * 128 + ((krow) ^ (((col) & 7) << 3)))

// exp2-domain: phi = ratio * exp(x.P'*sc - sc^2*||x||^2/2) = 2^( mfma(x, sc*log2e*P) + rc )
// rc = -0.5*sc^2*log2e*||x||^2 + log2(ratio);  sc = 64^-0.25 = 2^-1.5, ratio = 1/16
#define SCLOG2E 0.51006971688f          // sc * log2(e)
#define RC_COEF -0.09016844006f         // -0.5 * sc^2 * log2(e)
#define LOG2RATIO -4.0f                 // log2(1/16)

__device__ __forceinline__ unsigned short f2bf(float f) {
    union { float f; unsigned int u; } v; v.f = f;
    unsigned int r = v.u + 0x7FFFu + ((v.u >> 16) & 1u);   // RNE
    return (unsigned short)(r >> 16);
}
// HW packed f32->bf16 (RNE) via compiler intrinsic: low16 = bf16(lo), high16 = bf16(hi)
__device__ __forceinline__ unsigned int pack2bf(float lo, float hi) {
    union { __hip_bfloat162 h; unsigned int u; } c;
    c.h = __float22bfloat162_rn(make_float2(lo, hi));
    return c.u;
}
__device__ __forceinline__ float bf2f(unsigned int bits16) {   // low 16 bits -> f32
    union { unsigned int u; float f; } v; v.u = bits16 << 16; return v.f;
}
union bfrag { unsigned int u[4]; bf16x8 v; };

// ---------------- prep_pb: Pb frags (1 block) ----------------
// Pb frag f = kstep*16+nt: B[k][n] = SCLOG2E*P[n][k], n = nt*16+(l&15), k = kstep*32+(l>>4)*8+j.
__global__ __launch_bounds__(256)
void prep_pb_kernel(const float* __restrict__ P, unsigned short* __restrict__ Pb)
{
    const int t = threadIdx.x, l = t & 63, g = t >> 6;
    for (int f = g * 8; f < g * 8 + 8; f++) {
        const int kstep = f >> 4, nt = f & 15;
        const float* src = P + (nt * 16 + (l & 15)) * 64 + kstep * 32 + (l >> 4) * 8;
        bfrag fr;
        #pragma unroll
        for (int jp = 0; jp < 4; jp++)
            fr.u[jp] = pack2bf(SCLOG2E * src[2 * jp], SCLOG2E * src[2 * jp + 1]);
        *(bf16x8*)(Pb + f * 512 + l * 8) = fr.v;
    }
}

// ---------------- phi of a 128-row chunk -> swizzled LDS (bf16), 8 waves ----------------
// phi value for (row, feat) lands at u16 index PHI_OFF(feat, row).
__device__ __forceinline__ void phi_chunk8_swz(const float* __restrict__ X, int chunkBase,
                                               const unsigned short* __restrict__ Pb,
                                               unsigned short* phi_lds, float* rc)
{
    const int t = threadIdx.x, l = t & 63, w = t >> 6;
    if (t < 128) {   // per-row constant (exp2 domain)
        const float4* xr = (const float4*)(X + (size_t)(chunkBase + t) * 64);
        float s0 = 0.f, s1 = 0.f;
        #pragma unroll
        for (int j = 0; j < 16; j += 2) {
            float4 a = xr[j];     s0 += a.x*a.x + a.y*a.y + a.z*a.z + a.w*a.w;
            float4 b = xr[j + 1]; s1 += b.x*b.x + b.y*b.y + b.z*b.z + b.w*b.w;
        }
        rc[t] = RC_COEF * (s0 + s1) + LOG2RATIO;
    }
    // A-frags: wave w owns rows [chunkBase+16w, +16); m = l&15, k = (l>>4)*8 + j (+32)
    const float4* ar = (const float4*)(X + (size_t)(chunkBase + 16 * w + (l & 15)) * 64 + (l >> 4) * 8);
    float4 x0 = ar[0], x1 = ar[1], x2 = ar[8], x3 = ar[9];
    bfrag a0, a1;
    a0.u[0] = pack2bf(x0.x, x0.y); a0.u[1] = pack2bf(x0.z, x0.w);
    a0.u[2] = pack2bf(x1.x, x1.y); a0.u[3] = pack2bf(x1.z, x1.w);
    a1.u[0] = pack2bf(x2.x, x2.y); a1.u[1] = pack2bf(x2.z, x2.w);
    a1.u[2] = pack2bf(x3.x, x3.y); a1.u[3] = pack2bf(x3.z, x3.w);
    __syncthreads();   // rc ready
    const float4 rcv = *(const float4*)(rc + 16 * w + 4 * (l >> 4));   // rc rows for D regs 0..3
    #pragma unroll
    for (int nt = 0; nt < 16; nt++) {
        bf16x8 b0 = *(const bf16x8*)(Pb + nt * 512 + l * 8);
        bf16x8 b1 = *(const bf16x8*)(Pb + (16 + nt) * 512 + l * 8);
        f32x4 acc = (f32x4){rcv.x, rcv.y, rcv.z, rcv.w};   // C-in = rc (free add)
        acc = __builtin_amdgcn_mfma_f32_16x16x32_bf16(a0.v, b0, acc, 0, 0, 0);
        acc = __builtin_amdgcn_mfma_f32_16x16x32_bf16(a1.v, b1, acc, 0, 0, 0);
        float p0 = __builtin_amdgcn_exp2f(acc[0]);
        float p1 = __builtin_amdgcn_exp2f(acc[1]);
        float p2 = __builtin_amdgcn_exp2f(acc[2]);
        float p3 = __builtin_amdgcn_exp2f(acc[3]);
        const int col = nt * 16 + (l & 15);   // feature
        const int r0 = 16 * w + 4 * (l >> 4); // rows r0..r0+3 (bits 0..2 intact under XOR)
        unsigned int* dst = (unsigned int*)(phi_lds + PHI_OFF(col, r0));
        dst[0] = pack2bf(p0, p1);
        dst[1] = pack2bf(p2, p3);
    }
    __syncthreads();
}

// ---------------- kv: partials[blk] = phi(K)^T @ [V | 1], V staged once in LDS ----------------
__global__ __launch_bounds__(512, 4)
void kv_kernel(const float* __restrict__ Kp, const float* __restrict__ V,
               const unsigned short* __restrict__ Pb, unsigned int* __restrict__ partials)
{
    __shared__ __align__(16) unsigned short phi_lds[RFEAT * 128];   // 64 KB, swizzled
    __shared__ __align__(16) unsigned short v_lds[64 * 128];        // 16 KB, swizzled
    float* rc = (float*)v_lds;    // 512 B alias; rc dead before V stores (after phi's final sync)
    const int t = threadIdx.x, l = t & 63, w = t >> 6;   // w in [0,8)
    const int cb = blockIdx.x * 128;              // one 128-row chunk per block

    // T14 early-issue: thread t loads V col (t&63), krows [(t>>6)*16, +16) -> regs
    const int vcol = t & 63, vr0 = (t >> 6) * 16;
    float vreg[16];
    #pragma unroll
    for (int i = 0; i < 16; i++)
        vreg[i] = V[(size_t)(cb + vr0 + i) * 64 + vcol];

    phi_chunk8_swz(Kp, cb, Pb, phi_lds, rc);      // ends with __syncthreads (rc now dead)

    // convert V -> v_lds (bf16, swizzled): 2 x b128 stores per thread
    {
        unsigned int pk[8];
        #pragma unroll
        for (int i = 0; i < 8; i++) pk[i] = pack2bf(vreg[2 * i], vreg[2 * i + 1]);
        unsigned int* d0 = (unsigned int*)(v_lds + V_OFF(vcol, vr0));
        unsigned int* d1 = (unsigned int*)(v_lds + V_OFF(vcol, vr0 + 8));
        d0[0] = pk[0]; d0[1] = pk[1]; d0[2] = pk[2]; d0[3] = pk[3];
        d1[0] = pk[4]; d1[1] = pk[5]; d1[2] = pk[6]; d1[3] = pk[7];
    }
    __syncthreads();

    f32x4 acc[2][5];
    #pragma unroll
    for (int mt = 0; mt < 2; mt++)
        #pragma unroll
        for (int nt = 0; nt < 5; nt++) acc[mt][nt] = (f32x4){0.f, 0.f, 0.f, 0.f};

    bf16x8 ones;   // B-frag for ksum column: B[k][64]=1, rest 0 -> lanes with (l&15)==0
    #pragma unroll
    for (int j = 0; j < 8; j++) ones[j] = (short)(((l & 15) == 0) ? 0x3F80 : 0);

    #pragma unroll
    for (int ks = 0; ks < 4; ks++) {              // 4 k-steps of 32 krows
        const int krow0 = ks * 32 + (l >> 4) * 8;
        bf16x8 af[2];   // A = phi(K)^T: m=feature, k=krow; wave w owns feats [32w,+32)
        #pragma unroll
        for (int mt = 0; mt < 2; mt++)
            af[mt] = *(const bf16x8*)(phi_lds + PHI_OFF(32 * w + mt * 16 + (l & 15), krow0));
        bf16x8 bf4[4];  // B = V bf16 from LDS
        #pragma unroll
        for (int nt = 0; nt < 4; nt++)
            bf4[nt] = *(const bf16x8*)(v_lds + V_OFF(nt * 16 + (l & 15), krow0));
        #pragma unroll
        for (int mt = 0; mt < 2; mt++) {
            #pragma unroll
            for (int nt = 0; nt < 4; nt++)
                acc[mt][nt] = __builtin_amdgcn_mfma_f32_16x16x32_bf16(af[mt], bf4[nt], acc[mt][nt], 0, 0, 0);
            acc[mt][4] = __builtin_amdgcn_mfma_f32_16x16x32_bf16(af[mt], ones, acc[mt][4], 0, 0, 0);
        }
    }
    // partials slot: u32 word at [featpair][col], featpair = feat>>1, stride PCOL
    unsigned int* slot = partials + (size_t)blockIdx.x * PARTU;
    #pragma unroll
    for (int mt = 0; mt < 2; mt++) {
        const int fpb = 16 * w + mt * 8 + ((l >> 4) << 1);   // feat-pair row of regs 0,1
        #pragma unroll
        for (int nt = 0; nt < 5; nt++) {
            if (nt == 4 && (l & 15) != 0) continue;
            const int col = nt * 16 + (l & 15);              // nt==4 -> col 64 (ksum)
            slot[fpb * PCOL + col]       = pack2bf(acc[mt][nt][0], acc[mt][nt][1]);
            slot[(fpb + 1) * PCOL + col] = pack2bf(acc[mt][nt][2], acc[mt][nt][3]);
        }
    }
}

// ---------------- reduceA: sum 64 slots (bf16 pairs, f32 accum) -> p2[g][8448] float2 ----------------
__global__ __launch_bounds__(256)
void reduceA_kernel(const unsigned int* __restrict__ partials, float2* __restrict__ p2)
{
    const int idx = blockIdx.x * 256 + threadIdx.x;   // 33*256 == 8448 exactly
    const int g = blockIdx.y;
    const unsigned int* base = partials + (size_t)g * 64 * PARTU + idx;
    float lo0 = 0.f, hi0 = 0.f, lo1 = 0.f, hi1 = 0.f;
    #pragma unroll 4
    for (int s = 0; s < 64; s += 2) {
        unsigned int u0 = base[(size_t)s * PARTU];
        unsigned int u1 = base[(size_t)(s + 1) * PARTU];
        lo0 += bf2f(u0 & 0xFFFFu); hi0 += bf2f(u0 >> 16);
        lo1 += bf2f(u1 & 0xFFFFu); hi1 += bf2f(u1 >> 16);
    }
    p2[(size_t)g * PARTU + idx] = make_float2(lo0 + lo1, hi0 + hi1);
}

// ---------------- reduceB: sum groups -> Zb (bf16, B-frag octet layout) ----------------
// Zb element (m,n) at ushort ((m>>3)*80 + n)*8 + (m&7); col 64 = ksum.
__global__ __launch_bounds__(256)
void reduceB_kernel(const float2* __restrict__ p2, unsigned short* __restrict__ Zb)
{
    const int idx = blockIdx.x * 256 + threadIdx.x;   // 0..8447
    float sLo = 0.f, sHi = 0.f;
    #pragma unroll
    for (int g = 0; g < NGRP; g++) {
        float2 v = p2[(size_t)g * PARTU + idx];
        sLo += v.x; sHi += v.y;
    }
    const int fp = idx / PCOL, col = idx - fp * PCOL;
    if (col >= 65) return;               // pad col
    const int m0 = 2 * fp, m1 = m0 + 1;
    Zb[((m0 >> 3) * 80 + col) * 8 + (m0 & 7)] = f2bf(sLo);
    Zb[((m1 >> 3) * 80 + col) * 8 + (m1 & 7)] = f2bf(sHi);
}

// ---------------- phi of a 64-row chunk -> LDS [row][feat] (4 waves, for q_out) ----------------
__device__ __forceinline__ void phi_chunk_q(const float* __restrict__ X, int chunkBase,
                                            const unsigned short* __restrict__ Pb,
                                            unsigned short* phi_lds, float* rc)
{
    const int t = threadIdx.x, l = t & 63, w = t >> 6;
    if (t < 64) {
        const float4* xr = (const float4*)(X + (size_t)(chunkBase + t) * 64);
        float s0 = 0.f, s1 = 0.f;
        #pragma unroll
        for (int j = 0; j < 16; j += 2) {
            float4 a = xr[j];     s0 += a.x*a.x + a.y*a.y + a.z*a.z + a.w*a.w;
            float4 b = xr[j + 1]; s1 += b.x*b.x + b.y*b.y + b.z*b.z + b.w*b.w;
        }
        rc[t] = RC_COEF * (s0 + s1) + LOG2RATIO;
    }
    const float4* ar = (const float4*)(X + (size_t)(chunkBase + 16 * w + (l & 15)) * 64 + (l >> 4) * 8);
    float4 x0 = ar[0], x1 = ar[1], x2 = ar[8], x3 = ar[9];
    bfrag a0, a1;
    a0.u[0] = pack2bf(x0.x, x0.y); a0.u[1] = pack2bf(x0.z, x0.w);
    a0.u[2] = pack2bf(x1.x, x1.y); a0.u[3] = pack2bf(x1.z, x1.w);
    a1.u[0] = pack2bf(x2.x, x2.y); a1.u[1] = pack2bf(x2.z, x2.w);
    a1.u[2] = pack2bf(x3.x, x3.y); a1.u[3] = pack2bf(x3.z, x3.w);
    __syncthreads();
    const float4 rcv = *(const float4*)(rc + 16 * w + 4 * (l >> 4));
    #pragma unroll
    for (int nt = 0; nt < 16; nt++) {
        bf16x8 b0 = *(const bf16x8*)(Pb + nt * 512 + l * 8);
        bf16x8 b1 = *(const bf16x8*)(Pb + (16 + nt) * 512 + l * 8);
        f32x4 acc = (f32x4){rcv.x, rcv.y, rcv.z, rcv.w};
        acc = __builtin_amdgcn_mfma_f32_16x16x32_bf16(a0.v, b0, acc, 0, 0, 0);
        acc = __builtin_amdgcn_mfma_f32_16x16x32_bf16(a1.v, b1, acc, 0, 0, 0);
        float p0 = __builtin_amdgcn_exp2f(acc[0]);
        float p1 = __builtin_amdgcn_exp2f(acc[1]);
        float p2 = __builtin_amdgcn_exp2f(acc[2]);
        float p3 = __builtin_amdgcn_exp2f(acc[3]);
        const int col = nt * 16 + (l & 15);
        unsigned int w0 = pack2bf(p0, p1);
        unsigned int w1 = pack2bf(p2, p3);
        const int rb = (16 * w + (l >> 4) * 4) * LDQ + col;
        phi_lds[rb]           = (unsigned short)(w0);
        phi_lds[rb + LDQ]     = (unsigned short)(w0 >> 16);
        phi_lds[rb + 2 * LDQ] = (unsigned short)(w1);
        phi_lds[rb + 3 * LDQ] = (unsigned short)(w1 >> 16);
    }
    __syncthreads();
}

// ---------------- q_out: out = normalize( phi(Q) @ Zb ) ----------------
__global__ __launch_bounds__(256, 4)
void q_out_kernel(const float* __restrict__ Q, const unsigned short* __restrict__ Pb,
                  const unsigned short* __restrict__ Zb, float* __restrict__ out)
{
    __shared__ __align__(16) unsigned short phi_lds[64 * LDQ];   // [row][feat], padded
    __shared__ __align__(16) float rc[64];
    const int t = threadIdx.x, l = t & 63, w = t >> 6;
    const int base = blockIdx.x * 64;

    phi_chunk_q(Q, base, Pb, phi_lds, rc);

    f32x4 acc[5];
    #pragma unroll
    for (int nt = 0; nt < 5; nt++) acc[nt] = (f32x4){0.f, 0.f, 0.f, 0.f};

    #pragma unroll
    for (int ks = 0; ks < 8; ks++) {
        // A = phi(Q): m = qrow (wave w rows 16w..+16), k = feature
        bf16x8 a = *(const bf16x8*)(phi_lds + (16 * w + (l & 15)) * LDQ + ks * 32 + (l >> 4) * 8);
        #pragma unroll
        for (int nt = 0; nt < 5; nt++) {
            bf16x8 b = *(const bf16x8*)(Zb + ((ks * 4 + (l >> 4)) * 80 + nt * 16 + (l & 15)) * 8);
            acc[nt] = __builtin_amdgcn_mfma_f32_16x16x32_bf16(a, b, acc[nt], 0, 0, 0);
        }
    }
    // denom = output column 64 -> tile 4, lanes with (l&15)==0; broadcast within 16-group
    float inv[4];
    #pragma unroll
    for (int reg = 0; reg < 4; reg++) {
        float den = __shfl(acc[4][reg], (l & 48));
        inv[reg] = 1.0f / den;
    }
    const int row = base + 16 * w + (l >> 4) * 4;
    #pragma unroll
    for (int nt = 0; nt < 4; nt++)
        #pragma unroll
        for (int reg = 0; reg < 4; reg++)
            out[(size_t)(row + reg) * 64 + nt * 16 + (l & 15)] = acc[nt][reg] * inv[reg];
}

extern "C" void kernel_launch(void* const* d_in, const int* in_sizes, int n_in,
                              void* d_out, int out_size, void* d_ws, size_t ws_size,
                              hipStream_t stream) {
    const float* q = (const float*)d_in[0];
    const float* k = (const float*)d_in[1];
    const float* v = (const float*)d_in[2];
    const float* P = (const float*)d_in[3];
    float* out = (float*)d_out;

    unsigned short* Pb = (unsigned short*)d_ws;                      // 32 frags = 32KB
    unsigned short* Zb = Pb + 32 * 512;                              // 20480 u16 = 40KB
    float2* p2 = (float2*)((char*)d_ws + 73728);                     // 8*8448*8 = 540.7KB
    unsigned int* partials = (unsigned int*)((char*)d_ws + 73728 + 540672); // 512*8448*4 = 17.3MB

    prep_pb_kernel<<<1, 256, 0, stream>>>(P, Pb);
    kv_kernel<<<NBKV, 512, 0, stream>>>(k, v, Pb, partials);
    reduceA_kernel<<<dim3(33, NGRP), 256, 0, stream>>>(partials, p2);
    reduceB_kernel<<<33, 256, 0, stream>>>(p2, Zb);
    q_out_kernel<<<1024, 256, 0, stream>>>(q, Pb, Zb, out);
}

// Round 13
// 122.807 us; speedup vs baseline: 1.6529x; 1.0268x over previous
//
#include <hip/hip_runtime.h>
#include <hip/hip_bf16.h>
#include <math.h>

typedef __attribute__((ext_vector_type(8))) short bf16x8;
typedef __attribute__((ext_vector_type(4))) float f32x4;

#define RFEAT 256
#define NBKV 512                        // kv blocks (512 threads, 128 rows each) -> 2 blocks/CU
#define PCOL 66                         // partial cols: 64 v + ksum(64) + 1 pad
#define PARTU (128 * PCOL)              // 8448 u32 per slot (128 feat-pairs x 66 cols)
#define NGRP 8                          // reduceA groups (64 slots each)
#define LDQ 264                         // q_out phi stride (u16): 132%32=4 -> 2-way reads

// swizzled LDS offsets (u16 index): stride 128, XOR row bits 3..5 with low feat/col bits
#define PHI_OFF(feat, row) ((feat) * 128 + ((row) ^ (((feat) & 7) << 3)))
#define V_OFF(col, krow)   ((col) * 128 + ((krow) ^ (((col) & 7) << 3)))

// exp2-domain: phi = ratio * exp(x.P'*sc - sc^2*||x||^2/2) = 2^( mfma(x, sc*log2e*P) + rc )
// rc = -0.5*sc^2*log2e*||x||^2 + log2(ratio);  sc = 64^-0.25 = 2^-1.5, ratio = 1/16
#define SCLOG2E 0.51006971688f          // sc * log2(e)
#define RC_COEF -0.09016844006f         // -0.5 * sc^2 * log2(e)
#define LOG2RATIO -4.0f                 // log2(1/16)

__device__ __forceinline__ unsigned short f2bf(float f) {
    union { float f; unsigned int u; } v; v.f = f;
    unsigned int r = v.u + 0x7FFFu + ((v.u >> 16) & 1u);   // RNE
    return (unsigned short)(r >> 16);
}
// HW packed f32->bf16 (RNE) via compiler intrinsic: low16 = bf16(lo), high16 = bf16(hi)
__device__ __forceinline__ unsigned int pack2bf(float lo, float hi) {
    union { __hip_bfloat162 h; unsigned int u; } c;
    c.h = __float22bfloat162_rn(make_float2(lo, hi));
    return c.u;
}
__device__ __forceinline__ float bf2f(unsigned int bits16) {   // low 16 bits -> f32
    union { unsigned int u; float f; } v; v.u = bits16 << 16; return v.f;
}
union bfrag { unsigned int u[4]; bf16x8 v; };

// ---------------- prep_pb: Pb frags (1 block) ----------------
// Pb frag f = kstep*16+nt: B[k][n] = SCLOG2E*P[n][k], n = nt*16+(l&15), k = kstep*32+(l>>4)*8+j.
__global__ __launch_bounds__(256)
void prep_pb_kernel(const float* __restrict__ P, unsigned short* __restrict__ Pb)
{
    const int t = threadIdx.x, l = t & 63, g = t >> 6;
    for (int f = g * 8; f < g * 8 + 8; f++) {
        const int kstep = f >> 4, nt = f & 15;
        const float* src = P + (nt * 16 + (l & 15)) * 64 + kstep * 32 + (l >> 4) * 8;
        bfrag fr;
        #pragma unroll
        for (int jp = 0; jp < 4; jp++)
            fr.u[jp] = pack2bf(SCLOG2E * src[2 * jp], SCLOG2E * src[2 * jp + 1]);
        *(bf16x8*)(Pb + f * 512 + l * 8) = fr.v;
    }
}

// ---------------- A-frags + rc from registers (shared by both phi variants) ----------------
// Loads row (chunkBase + 16w + (l&15)) elements [(l>>4)*8,+8) and [32+(l>>4)*8,+8);
// builds a0,a1 bf16 frags and the per-D-reg rc four-vector via in-wave shfl reduction.
__device__ __forceinline__ void phi_afrag_rc(const float* __restrict__ X, int chunkBase,
                                             int l, int w, bfrag& a0, bfrag& a1, float4& rcv)
{
    const float4* ar = (const float4*)(X + (size_t)(chunkBase + 16 * w + (l & 15)) * 64 + (l >> 4) * 8);
    float4 x0 = ar[0], x1 = ar[1], x2 = ar[8], x3 = ar[9];
    a0.u[0] = pack2bf(x0.x, x0.y); a0.u[1] = pack2bf(x0.z, x0.w);
    a0.u[2] = pack2bf(x1.x, x1.y); a0.u[3] = pack2bf(x1.z, x1.w);
    a1.u[0] = pack2bf(x2.x, x2.y); a1.u[1] = pack2bf(x2.z, x2.w);
    a1.u[2] = pack2bf(x3.x, x3.y); a1.u[3] = pack2bf(x3.z, x3.w);
    // ssq: the 4 lane-groups with equal (l&15) hold disjoint 16-subsets of the row's 64 values
    float ssq = x0.x*x0.x + x0.y*x0.y + x0.z*x0.z + x0.w*x0.w
              + x1.x*x1.x + x1.y*x1.y + x1.z*x1.z + x1.w*x1.w
              + x2.x*x2.x + x2.y*x2.y + x2.z*x2.z + x2.w*x2.w
              + x3.x*x3.x + x3.y*x3.y + x3.z*x3.z + x3.w*x3.w;
    ssq += __shfl_xor(ssq, 16);
    ssq += __shfl_xor(ssq, 32);
    const float rcrow = RC_COEF * ssq + LOG2RATIO;     // rc of local row (l&15)
    const int r0 = 4 * (l >> 4);                       // D rows r0..r0+3
    rcv.x = __shfl(rcrow, r0 + 0);
    rcv.y = __shfl(rcrow, r0 + 1);
    rcv.z = __shfl(rcrow, r0 + 2);
    rcv.w = __shfl(rcrow, r0 + 3);
}

// ---------------- phi of a 128-row chunk -> swizzled LDS (bf16), 8 waves ----------------
// phi value for (row, feat) lands at u16 index PHI_OFF(feat, row). Ends with syncthreads.
__device__ __forceinline__ void phi_chunk8_swz(const float* __restrict__ X, int chunkBase,
                                               const unsigned short* __restrict__ Pb,
                                               unsigned short* phi_lds)
{
    const int t = threadIdx.x, l = t & 63, w = t >> 6;
    bfrag a0, a1; float4 rcv;
    phi_afrag_rc(X, chunkBase, l, w, a0, a1, rcv);
    #pragma unroll
    for (int nt = 0; nt < 16; nt++) {
        bf16x8 b0 = *(const bf16x8*)(Pb + nt * 512 + l * 8);
        bf16x8 b1 = *(const bf16x8*)(Pb + (16 + nt) * 512 + l * 8);
        f32x4 acc = (f32x4){rcv.x, rcv.y, rcv.z, rcv.w};   // C-in = rc (free add)
        acc = __builtin_amdgcn_mfma_f32_16x16x32_bf16(a0.v, b0, acc, 0, 0, 0);
        acc = __builtin_amdgcn_mfma_f32_16x16x32_bf16(a1.v, b1, acc, 0, 0, 0);
        float p0 = __builtin_amdgcn_exp2f(acc[0]);
        float p1 = __builtin_amdgcn_exp2f(acc[1]);
        float p2 = __builtin_amdgcn_exp2f(acc[2]);
        float p3 = __builtin_amdgcn_exp2f(acc[3]);
        const int col = nt * 16 + (l & 15);   // feature
        const int r0 = 16 * w + 4 * (l >> 4); // rows r0..r0+3 (bits 0..2 intact under XOR)
        unsigned int* dst = (unsigned int*)(phi_lds + PHI_OFF(col, r0));
        dst[0] = pack2bf(p0, p1);
        dst[1] = pack2bf(p2, p3);
    }
    __syncthreads();
}

// ---------------- kv: partials[blk] = phi(K)^T @ [V | 1], V staged once in LDS ----------------
__global__ __launch_bounds__(512, 4)
void kv_kernel(const float* __restrict__ Kp, const float* __restrict__ V,
               const unsigned short* __restrict__ Pb, unsigned int* __restrict__ partials)
{
    __shared__ __align__(16) unsigned short phi_lds[RFEAT * 128];   // 64 KB, swizzled
    __shared__ __align__(16) unsigned short v_lds[64 * 128];        // 16 KB, swizzled
    const int t = threadIdx.x, l = t & 63, w = t >> 6;   // w in [0,8)
    const int cb = blockIdx.x * 128;              // one 128-row chunk per block

    // T14 early-issue: thread t loads V col (t&63), krows [(t>>6)*16, +16) -> regs
    const int vcol = t & 63, vr0 = (t >> 6) * 16;
    float vreg[16];
    #pragma unroll
    for (int i = 0; i < 16; i++)
        vreg[i] = V[(size_t)(cb + vr0 + i) * 64 + vcol];

    phi_chunk8_swz(Kp, cb, Pb, phi_lds);          // ends with __syncthreads

    // convert V -> v_lds (bf16, swizzled): 2 x b128 stores per thread
    {
        unsigned int pk[8];
        #pragma unroll
        for (int i = 0; i < 8; i++) pk[i] = pack2bf(vreg[2 * i], vreg[2 * i + 1]);
        unsigned int* d0 = (unsigned int*)(v_lds + V_OFF(vcol, vr0));
        unsigned int* d1 = (unsigned int*)(v_lds + V_OFF(vcol, vr0 + 8));
        d0[0] = pk[0]; d0[1] = pk[1]; d0[2] = pk[2]; d0[3] = pk[3];
        d1[0] = pk[4]; d1[1] = pk[5]; d1[2] = pk[6]; d1[3] = pk[7];
    }
    __syncthreads();

    f32x4 acc[2][5];
    #pragma unroll
    for (int mt = 0; mt < 2; mt++)
        #pragma unroll
        for (int nt = 0; nt < 5; nt++) acc[mt][nt] = (f32x4){0.f, 0.f, 0.f, 0.f};

    bf16x8 ones;   // B-frag for ksum column: B[k][64]=1, rest 0 -> lanes with (l&15)==0
    #pragma unroll
    for (int j = 0; j < 8; j++) ones[j] = (short)(((l & 15) == 0) ? 0x3F80 : 0);

    #pragma unroll
    for (int ks = 0; ks < 4; ks++) {              // 4 k-steps of 32 krows
        const int krow0 = ks * 32 + (l >> 4) * 8;
        bf16x8 af[2];   // A = phi(K)^T: m=feature, k=krow; wave w owns feats [32w,+32)
        #pragma unroll
        for (int mt = 0; mt < 2; mt++)
            af[mt] = *(const bf16x8*)(phi_lds + PHI_OFF(32 * w + mt * 16 + (l & 15), krow0));
        bf16x8 bf4[4];  // B = V bf16 from LDS
        #pragma unroll
        for (int nt = 0; nt < 4; nt++)
            bf4[nt] = *(const bf16x8*)(v_lds + V_OFF(nt * 16 + (l & 15), krow0));
        #pragma unroll
        for (int mt = 0; mt < 2; mt++) {
            #pragma unroll
            for (int nt = 0; nt < 4; nt++)
                acc[mt][nt] = __builtin_amdgcn_mfma_f32_16x16x32_bf16(af[mt], bf4[nt], acc[mt][nt], 0, 0, 0);
            acc[mt][4] = __builtin_amdgcn_mfma_f32_16x16x32_bf16(af[mt], ones, acc[mt][4], 0, 0, 0);
        }
    }
    // partials slot: u32 word at [featpair][col], featpair = feat>>1, stride PCOL
    unsigned int* slot = partials + (size_t)blockIdx.x * PARTU;
    #pragma unroll
    for (int mt = 0; mt < 2; mt++) {
        const int fpb = 16 * w + mt * 8 + ((l >> 4) << 1);   // feat-pair row of regs 0,1
        #pragma unroll
        for (int nt = 0; nt < 5; nt++) {
            if (nt == 4 && (l & 15) != 0) continue;
            const int col = nt * 16 + (l & 15);              // nt==4 -> col 64 (ksum)
            slot[fpb * PCOL + col]       = pack2bf(acc[mt][nt][0], acc[mt][nt][1]);
            slot[(fpb + 1) * PCOL + col] = pack2bf(acc[mt][nt][2], acc[mt][nt][3]);
        }
    }
}

// ---------------- reduceA: sum 64 slots (bf16 pairs, f32 accum) -> p2[g][8448] float2 ----------------
__global__ __launch_bounds__(256)
void reduceA_kernel(const unsigned int* __restrict__ partials, float2* __restrict__ p2)
{
    const int idx = blockIdx.x * 256 + threadIdx.x;   // 33*256 == 8448 exactly
    const int g = blockIdx.y;
    const unsigned int* base = partials + (size_t)g * 64 * PARTU + idx;
    float lo0 = 0.f, hi0 = 0.f, lo1 = 0.f, hi1 = 0.f;
    #pragma unroll 4
    for (int s = 0; s < 64; s += 2) {
        unsigned int u0 = base[(size_t)s * PARTU];
        unsigned int u1 = base[(size_t)(s + 1) * PARTU];
        lo0 += bf2f(u0 & 0xFFFFu); hi0 += bf2f(u0 >> 16);
        lo1 += bf2f(u1 & 0xFFFFu); hi1 += bf2f(u1 >> 16);
    }
    p2[(size_t)g * PARTU + idx] = make_float2(lo0 + lo1, hi0 + hi1);
}

// ---------------- reduceB: sum groups -> Zb (bf16, B-frag octet layout) ----------------
// Zb element (m,n) at ushort ((m>>3)*80 + n)*8 + (m&7); col 64 = ksum.
__global__ __launch_bounds__(256)
void reduceB_kernel(const float2* __restrict__ p2, unsigned short* __restrict__ Zb)
{
    const int idx = blockIdx.x * 256 + threadIdx.x;   // 0..8447
    float sLo = 0.f, sHi = 0.f;
    #pragma unroll
    for (int g = 0; g < NGRP; g++) {
        float2 v = p2[(size_t)g * PARTU + idx];
        sLo += v.x; sHi += v.y;
    }
    const int fp = idx / PCOL, col = idx - fp * PCOL;
    if (col >= 65) return;               // pad col
    const int m0 = 2 * fp, m1 = m0 + 1;
    Zb[((m0 >> 3) * 80 + col) * 8 + (m0 & 7)] = f2bf(sLo);
    Zb[((m1 >> 3) * 80 + col) * 8 + (m1 & 7)] = f2bf(sHi);
}

// ---------------- phi of a 64-row chunk -> LDS [row][feat] (4 waves, for q_out) ----------------
__device__ __forceinline__ void phi_chunk_q(const float* __restrict__ X, int chunkBase,
                                            const unsigned short* __restrict__ Pb,
                                            unsigned short* phi_lds)
{
    const int t = threadIdx.x, l = t & 63, w = t >> 6;
    bfrag a0, a1; float4 rcv;
    phi_afrag_rc(X, chunkBase, l, w, a0, a1, rcv);
    #pragma unroll
    for (int nt = 0; nt < 16; nt++) {
        bf16x8 b0 = *(const bf16x8*)(Pb + nt * 512 + l * 8);
        bf16x8 b1 = *(const bf16x8*)(Pb + (16 + nt) * 512 + l * 8);
        f32x4 acc = (f32x4){rcv.x, rcv.y, rcv.z, rcv.w};
        acc = __builtin_amdgcn_mfma_f32_16x16x32_bf16(a0.v, b0, acc, 0, 0, 0);
        acc = __builtin_amdgcn_mfma_f32_16x16x32_bf16(a1.v, b1, acc, 0, 0, 0);
        float p0 = __builtin_amdgcn_exp2f(acc[0]);
        float p1 = __builtin_amdgcn_exp2f(acc[1]);
        float p2 = __builtin_amdgcn_exp2f(acc[2]);
        float p3 = __builtin_amdgcn_exp2f(acc[3]);
        const int col = nt * 16 + (l & 15);
        unsigned int w0 = pack2bf(p0, p1);
        unsigned int w1 = pack2bf(p2, p3);
        const int rb = (16 * w + (l >> 4) * 4) * LDQ + col;
        phi_lds[rb]           = (unsigned short)(w0);
        phi_lds[rb + LDQ]     = (unsigned short)(w0 >> 16);
        phi_lds[rb + 2 * LDQ] = (unsigned short)(w1);
        phi_lds[rb + 3 * LDQ] = (unsigned short)(w1 >> 16);
    }
    __syncthreads();
}

// ---------------- q_out: out = normalize( phi(Q) @ Zb ) ----------------
__global__ __launch_bounds__(256, 4)
void q_out_kernel(const float* __restrict__ Q, const unsigned short* __restrict__ Pb,
                  const unsigned short* __restrict__ Zb, float* __restrict__ out)
{
    __shared__ __align__(16) unsigned short phi_lds[64 * LDQ];   // [row][feat], padded
    const int t = threadIdx.x, l = t & 63, w = t >> 6;
    const int base = blockIdx.x * 64;

    phi_chunk_q(Q, base, Pb, phi_lds);

    f32x4 acc[5];
    #pragma unroll
    for (int nt = 0; nt < 5; nt++) acc[nt] = (f32x4){0.f, 0.f, 0.f, 0.f};

    #pragma unroll
    for (int ks = 0; ks < 8; ks++) {
        // A = phi(Q): m = qrow (wave w rows 16w..+16), k = feature
        bf16x8 a = *(const bf16x8*)(phi_lds + (16 * w + (l & 15)) * LDQ + ks * 32 + (l >> 4) * 8);
        #pragma unroll
        for (int nt = 0; nt < 5; nt++) {
            bf16x8 b = *(const bf16x8*)(Zb + ((ks * 4 + (l >> 4)) * 80 + nt * 16 + (l & 15)) * 8);
            acc[nt] = __builtin_amdgcn_mfma_f32_16x16x32_bf16(a, b, acc[nt], 0, 0, 0);
        }
    }
    // denom = output column 64 -> tile 4, lanes with (l&15)==0; broadcast within 16-group
    float inv[4];
    #pragma unroll
    for (int reg = 0; reg < 4; reg++) {
        float den = __shfl(acc[4][reg], (l & 48));
        inv[reg] = 1.0f / den;
    }
    const int row = base + 16 * w + (l >> 4) * 4;
    #pragma unroll
    for (int nt = 0; nt < 4; nt++)
        #pragma unroll
        for (int reg = 0; reg < 4; reg++)
            out[(size_t)(row + reg) * 64 + nt * 16 + (l & 15)] = acc[nt][reg] * inv[reg];
}

extern "C" void kernel_launch(void* const* d_in, const int* in_sizes, int n_in,
                              void* d_out, int out_size, void* d_ws, size_t ws_size,
                              hipStream_t stream) {
    const float* q = (const float*)d_in[0];
    const float* k = (const float*)d_in[1];
    const float* v = (const float*)d_in[2];
    const float* P = (const float*)d_in[3];
    float* out = (float*)d_out;

    unsigned short* Pb = (unsigned short*)d_ws;                      // 32 frags = 32KB
    unsigned short* Zb = Pb + 32 * 512;                              // 20480 u16 = 40KB
    float2* p2 = (float2*)((char*)d_ws + 73728);                     // 8*8448*8 = 540.7KB
    unsigned int* partials = (unsigned int*)((char*)d_ws + 73728 + 540672); // 512*8448*4 = 17.3MB

    prep_pb_kernel<<<1, 256, 0, stream>>>(P, Pb);
    kv_kernel<<<NBKV, 512, 0, stream>>>(k, v, Pb, partials);
    reduceA_kernel<<<dim3(33, NGRP), 256, 0, stream>>>(partials, p2);
    reduceB_kernel<<<33, 256, 0, stream>>>(p2, Zb);
    q_out_kernel<<<1024, 256, 0, stream>>>(q, Pb, Zb, out);
}